// Round 12
// baseline (257.946 us; speedup 1.0000x reference)
//
#include <hip/hip_runtime.h>
#include <hip/hip_fp16.h>

#define DD 128

typedef __attribute__((ext_vector_type(8))) short short8;
typedef __attribute__((ext_vector_type(8))) unsigned short ushort8;
typedef __attribute__((ext_vector_type(4))) float floatx4;
typedef unsigned int uint32;

__device__ __forceinline__ float sp(float x) {
    return fmaxf(x, 0.0f) + __logf(1.0f + __expf(-fabsf(x)));
}

__device__ __forceinline__ unsigned short f2bf(float f) {
    union { float f; uint32 u; } c; c.f = f;
    const uint32 u = c.u;
    return (unsigned short)((u + 0x7fffu + ((u >> 16) & 1u)) >> 16);
}

__device__ __forceinline__ unsigned short f2h(float f) {
    __half h = __float2half(f);
    return __builtin_bit_cast(unsigned short, h);
}

// ---------- preconvert ----------
// Weights: f32 [128][128] -> bf16 in MFMA-FRAGMENT ORDER:
//   frag r = (nt*4+kk)*64 + lane  holds  W[nt*16+(lane&15)][((kk*4+(lane>>4))*8 .. +8)]
// so a wave's B-fragment load is one coalesced 1KB read at base + r*16B.
// Also converts g -> fp16 for agg.
__global__ __launch_bounds__(256)
void convert_w(const float* __restrict__ Wj, const float* __restrict__ Wi,
               const float* __restrict__ rw1, const float* __restrict__ rw2,
               const float* __restrict__ Wf, unsigned short* __restrict__ out,
               const float* __restrict__ g, unsigned short* __restrict__ gh,
               int gchunks)
{
    if ((int)blockIdx.x >= 72) {
        const int gid = ((int)blockIdx.x - 72) * 256 + threadIdx.x;  // 8-float chunk
        if (gid < gchunks) {
            const float4 f0 = reinterpret_cast<const float4*>(g)[2 * gid];
            const float4 f1 = reinterpret_cast<const float4*>(g)[2 * gid + 1];
            ushort8 o;
            o[0] = f2h(f0.x); o[1] = f2h(f0.y); o[2] = f2h(f0.z); o[3] = f2h(f0.w);
            o[4] = f2h(f1.x); o[5] = f2h(f1.y); o[6] = f2h(f1.z); o[7] = f2h(f1.w);
            reinterpret_cast<ushort8*>(gh)[gid] = o;
        }
        return;
    }
    const int gid = blockIdx.x * 256 + threadIdx.x;
    const int mat = gid >> 11;
    const int r   = gid & 2047;
    const int ln  = r & 63;
    const int ntkk = r >> 6;                      // 0..31
    const float* src;
    if      (mat == 0) src = Wj;
    else if (mat == 1) src = Wi;
    else if (mat <= 4) src = rw1 + (size_t)(mat - 2) * 16384;
    else if (mat <= 7) src = rw2 + (size_t)(mat - 5) * 16384;
    else               src = Wf;
    const int row = (ntkk >> 2) * 16 + (ln & 15);
    const int c0  = ((ntkk & 3) * 4 + (ln >> 4)) * 8;
    const float* s = src + row * DD + c0;
    const float4 a = *reinterpret_cast<const float4*>(s);
    const float4 b = *reinterpret_cast<const float4*>(s + 4);
    ushort8 u8;
    u8[0] = f2bf(a.x); u8[1] = f2bf(a.y); u8[2] = f2bf(a.z); u8[3] = f2bf(a.w);
    u8[4] = f2bf(b.x); u8[5] = f2bf(b.y); u8[6] = f2bf(b.z); u8[7] = f2bf(b.w);
    *reinterpret_cast<ushort8*>(out + (size_t)mat * 16384 + (size_t)r * 8) = u8;
}

// linear 32KB copy (layout-agnostic)
__device__ __forceinline__ void stage_wb(const unsigned short* __restrict__ Wb,
                                         unsigned short* wl, int t)
{
    #pragma unroll
    for (int i = 0; i < 8; ++i) {
        const int c = t + i * 256;
        *reinterpret_cast<ushort8*>(wl + c * 8) =
            *reinterpret_cast<const ushort8*>(Wb + c * 8);
    }
}

__device__ __forceinline__ void load_afrag_act(const float* __restrict__ X,
                                               int m, int q, int n, short8 af[4])
{
    const int mm = m < n ? m : n - 1;
    const float* row = X + (size_t)mm * DD + q * 8;
    #pragma unroll
    for (int kk = 0; kk < 4; ++kk) {
        const float4 a = *reinterpret_cast<const float4*>(row + kk * 32);
        const float4 b = *reinterpret_cast<const float4*>(row + kk * 32 + 4);
        ushort8 u;
        u[0] = f2bf(sp(a.x)); u[1] = f2bf(sp(a.y)); u[2] = f2bf(sp(a.z)); u[3] = f2bf(sp(a.w));
        u[4] = f2bf(sp(b.x)); u[5] = f2bf(sp(b.y)); u[6] = f2bf(sp(b.z)); u[7] = f2bf(sp(b.w));
        af[kk] = __builtin_bit_cast(short8, u);
    }
}

// 16x128 per-wave GEMM; wsrc may be LDS (dual) or global (tail), frag-order layout
__device__ __forceinline__ void mfma_gemm(const unsigned short* __restrict__ wsrc,
                                          const short8 af[4], int lane, floatx4 acc[8])
{
    #pragma unroll
    for (int nt = 0; nt < 8; ++nt) {
        #pragma unroll
        for (int kk = 0; kk < 4; ++kk) {
            const short8 bfr = *reinterpret_cast<const short8*>(
                wsrc + (size_t)(((nt * 4 + kk) << 6) + lane) * 8);
            acc[nt] = __builtin_amdgcn_mfma_f32_16x16x32_bf16(af[kk], bfr, acc[nt], 0, 0, 0);
        }
    }
}

// A = act(act(x)@Wj.T+bj) [bf16], v = act(act(x)@Wi.T+bi) [f32]
__global__ __launch_bounds__(256, 4)
void dual_gemm(const float* __restrict__ x,
               const unsigned short* __restrict__ Wb,
               const float* __restrict__ bj, const float* __restrict__ bi,
               unsigned short* __restrict__ Aout, float* __restrict__ vout, int n)
{
    __shared__ __align__(16) unsigned short wl[128 * 128];
    const int t = threadIdx.x;
    const int lane = t & 63, wv = t >> 6;
    const int cl = lane & 15, q = lane >> 4;
    const int m0 = blockIdx.x * 64 + wv * 16;

    short8 af[4];
    load_afrag_act(x, m0 + cl, q, n, af);

    stage_wb(Wb, wl, t);
    __syncthreads();

    floatx4 acc[8];
    #pragma unroll
    for (int nt = 0; nt < 8; ++nt) acc[nt] = (floatx4){0.f, 0.f, 0.f, 0.f};
    mfma_gemm(wl, af, lane, acc);

    #pragma unroll
    for (int nt = 0; nt < 8; ++nt) {
        const int col = nt * 16 + cl;
        const float bb = bj[col];
        #pragma unroll
        for (int r = 0; r < 4; ++r) {
            const int row = m0 + q * 4 + r;
            if (row < n) Aout[(size_t)row * DD + col] = f2bf(sp(acc[nt][r] + bb));
        }
    }

    __syncthreads();
    stage_wb(Wb + 16384, wl, t);
    __syncthreads();

    #pragma unroll
    for (int nt = 0; nt < 8; ++nt) acc[nt] = (floatx4){0.f, 0.f, 0.f, 0.f};
    mfma_gemm(wl, af, lane, acc);

    #pragma unroll
    for (int nt = 0; nt < 8; ++nt) {
        const int col = nt * 16 + cl;
        const float bb = bi[col];
        #pragma unroll
        for (int r = 0; r < 4; ++r) {
            const int row = m0 + q * 4 + r;
            if (row < n) vout[(size_t)row * DD + col] = sp(acc[nt][r] + bb);
        }
    }
}

// fused tail: 3 residual layers + final output.
// BARRIER-FREE: B-fragments read directly from global (frag-order, coalesced
// 1KB/instr, L2-hot). LDS = 16KB hl only (same-wave bounce). 4 blocks/CU.
__global__ __launch_bounds__(256, 4)
void tail_kernel(const float* __restrict__ vin, const float* __restrict__ x,
                 const unsigned short* __restrict__ Wb,
                 const float* __restrict__ rb1, const float* __restrict__ rb2,
                 const float* __restrict__ bf, const float* __restrict__ u,
                 float* __restrict__ out, int n)
{
    __shared__ __align__(16) unsigned short hl[64 * 128];   // 16 KB
    const int t = threadIdx.x;
    const int lane = t & 63, wv = t >> 6;
    const int cl = lane & 15, q = lane >> 4;
    const int mb = blockIdx.x * 64;
    const int ml2 = wv * 16 + cl;

    // v accumulator direct from global (D-layout; L2/L3-resident)
    floatx4 vac[8];
    #pragma unroll
    for (int nt = 0; nt < 8; ++nt) {
        #pragma unroll
        for (int r = 0; r < 4; ++r) {
            const int row = mb + wv * 16 + q * 4 + r;
            const int col = nt * 16 + cl;
            vac[nt][r] = (row < n) ? vin[(size_t)row * DD + col] : 0.f;
        }
    }

    // layer-0 A-fragments straight from global vin
    short8 af[4];
    load_afrag_act(vin, mb + wv * 16 + cl, q, n, af);

    #pragma unroll
    for (int l = 0; l < 3; ++l) {
        const unsigned short* W1 = Wb + (size_t)(2 + l) * 16384;
        const unsigned short* W2 = Wb + (size_t)(5 + l) * 16384;

        if (l > 0) {
            // af = bf16(sp(vac)) via per-wave hl bounce (same-wave LDS, ordered)
            #pragma unroll
            for (int nt = 0; nt < 8; ++nt) {
                const int col = nt * 16 + cl;
                const int ch = col >> 3;
                #pragma unroll
                for (int r = 0; r < 4; ++r) {
                    const int ml = wv * 16 + q * 4 + r;
                    hl[ml * 128 + ((ch ^ (ml & 15)) << 3) + (col & 7)] = f2bf(sp(vac[nt][r]));
                }
            }
            #pragma unroll
            for (int kk = 0; kk < 4; ++kk)
                af[kk] = *reinterpret_cast<const short8*>(hl + ml2 * 128 + (((kk * 4 + q) ^ cl) << 3));
        }

        floatx4 acc[8];
        #pragma unroll
        for (int nt = 0; nt < 8; ++nt) acc[nt] = (floatx4){0.f, 0.f, 0.f, 0.f};
        mfma_gemm(W1, af, lane, acc);

        // h2 = act(acc + b1) -> hl, then second A-fragments
        const float* b1 = rb1 + (size_t)l * DD;
        #pragma unroll
        for (int nt = 0; nt < 8; ++nt) {
            const int col = nt * 16 + cl;
            const int ch = col >> 3;
            const float bb = b1[col];
            #pragma unroll
            for (int r = 0; r < 4; ++r) {
                const int ml = wv * 16 + q * 4 + r;
                hl[ml * 128 + ((ch ^ (ml & 15)) << 3) + (col & 7)] = f2bf(sp(acc[nt][r] + bb));
            }
        }
        short8 af2[4];
        #pragma unroll
        for (int kk = 0; kk < 4; ++kk)
            af2[kk] = *reinterpret_cast<const short8*>(hl + ml2 * 128 + (((kk * 4 + q) ^ cl) << 3));

        // second GEMM accumulates directly into vac (residual add fused)
        mfma_gemm(W2, af2, lane, vac);
        const float* b2 = rb2 + (size_t)l * DD;
        #pragma unroll
        for (int nt = 0; nt < 8; ++nt) {
            const float bb = b2[nt * 16 + cl];
            #pragma unroll
            for (int r = 0; r < 4; ++r) vac[nt][r] += bb;
        }
    }

    // final: out = u*x + act(v)@Wf.T + bf
    #pragma unroll
    for (int nt = 0; nt < 8; ++nt) {
        const int col = nt * 16 + cl;
        const int ch = col >> 3;
        #pragma unroll
        for (int r = 0; r < 4; ++r) {
            const int ml = wv * 16 + q * 4 + r;
            hl[ml * 128 + ((ch ^ (ml & 15)) << 3) + (col & 7)] = f2bf(sp(vac[nt][r]));
        }
    }
    short8 aff[4];
    #pragma unroll
    for (int kk = 0; kk < 4; ++kk)
        aff[kk] = *reinterpret_cast<const short8*>(hl + ml2 * 128 + (((kk * 4 + q) ^ cl) << 3));

    floatx4 acc[8];
    #pragma unroll
    for (int nt = 0; nt < 8; ++nt) acc[nt] = (floatx4){0.f, 0.f, 0.f, 0.f};
    mfma_gemm(Wb + (size_t)8 * 16384, aff, lane, acc);

    #pragma unroll
    for (int nt = 0; nt < 8; ++nt) {
        const int col = nt * 16 + cl;
        const float bb = bf[col];
        const float uu = u[col];
        #pragma unroll
        for (int r = 0; r < 4; ++r) {
            const int row = mb + wv * 16 + q * 4 + r;
            if (row < n)
                out[(size_t)row * DD + col] =
                    acc[nt][r] + bb + uu * x[(size_t)row * DD + col];
        }
    }
}

// ---------- CSR build ----------

__global__ __launch_bounds__(256)
void hist_kernel(const int* __restrict__ idx_i, int* __restrict__ cnt, int E)
{
    const int e = blockIdx.x * 256 + threadIdx.x;
    if (e < E) atomicAdd(&cnt[idx_i[e]], 1);
}

__global__ __launch_bounds__(256)
void scan_reduce(const int* __restrict__ cnt, int* __restrict__ bsum, int n)
{
    __shared__ int wsum[4];
    const int t = threadIdx.x;
    const int lane = t & 63, wv = t >> 6;
    const int i0 = blockIdx.x * 1024 + t * 4;
    int s = 0;
    #pragma unroll
    for (int k = 0; k < 4; ++k) if (i0 + k < n) s += cnt[i0 + k];
    #pragma unroll
    for (int d = 1; d < 64; d <<= 1) s += __shfl_down(s, d, 64);
    if (lane == 0) wsum[wv] = s;
    __syncthreads();
    if (t == 0) bsum[blockIdx.x] = wsum[0] + wsum[1] + wsum[2] + wsum[3];
}

// local exclusive scan + block offset (bsum scanned in-kernel); zeroes cnt2
__global__ __launch_bounds__(256)
void scan_apply(const int* __restrict__ cnt, const int* __restrict__ bsum,
                int* __restrict__ off, int* __restrict__ cnt2, int n, int nb)
{
    __shared__ int wsum[4];
    const int t = threadIdx.x;
    const int lane = t & 63, wv = t >> 6;

    int bval = (lane < nb && lane < (int)blockIdx.x) ? bsum[lane] : 0;
    #pragma unroll
    for (int d = 32; d >= 1; d >>= 1) bval += __shfl_down(bval, d, 64);
    const int blk_off = __shfl(bval, 0, 64);

    const int i0 = blockIdx.x * 1024 + t * 4;
    const int v0 = (i0 + 0 < n) ? cnt[i0 + 0] : 0;
    const int v1 = (i0 + 1 < n) ? cnt[i0 + 1] : 0;
    const int v2 = (i0 + 2 < n) ? cnt[i0 + 2] : 0;
    const int v3 = (i0 + 3 < n) ? cnt[i0 + 3] : 0;
    const int s = v0 + v1 + v2 + v3;
    int incl = s;
    #pragma unroll
    for (int d = 1; d < 64; d <<= 1) {
        const int y = __shfl_up(incl, d, 64);
        if (lane >= d) incl += y;
    }
    if (lane == 63) wsum[wv] = incl;
    __syncthreads();
    int woff = blk_off;
    #pragma unroll
    for (int w = 0; w < 4; ++w) if (w < wv) woff += wsum[w];
    const int excl = woff + incl - s;
    if (i0 + 0 < n) { off[i0 + 0] = excl;                cnt2[i0 + 0] = 0; }
    if (i0 + 1 < n) { off[i0 + 1] = excl + v0;           cnt2[i0 + 1] = 0; }
    if (i0 + 2 < n) { off[i0 + 2] = excl + v0 + v1;      cnt2[i0 + 2] = 0; }
    if (i0 + 3 < n) { off[i0 + 3] = excl + v0 + v1 + v2; cnt2[i0 + 3] = 0; }
}

__global__ __launch_bounds__(256)
void scatter_kernel(const int* __restrict__ idx_i, const int* __restrict__ idx_j,
                    const int* __restrict__ off, int* __restrict__ cnt2,
                    int2* __restrict__ spair, int E)
{
    const int e = blockIdx.x * 256 + threadIdx.x;
    if (e < E) {
        const int i = idx_i[e];
        const int p = off[i] + atomicAdd(&cnt2[i], 1);
        spair[p] = make_int2(e, idx_j[e]);
    }
}

// grid-stride waves over atoms; R4/R7-proven load structure.
// GH=1: fp16-packed gate math reading preconverted g-half rows.
// GH=0: exact R7 f32 body (fallback).
template<int GH>
__global__ __launch_bounds__(256, 4)
void agg_kernel(const int* __restrict__ off, const int* __restrict__ cnt,
                const int2* __restrict__ spair,
                const unsigned short* __restrict__ gh,
                const float* __restrict__ g,
                const float* __restrict__ Wg, const float* __restrict__ bg,
                const unsigned short* __restrict__ A, float* __restrict__ v, int N)
{
    const int t = threadIdx.x;
    const int lane = t & 63;
    const int wid0 = blockIdx.x * 4 + (t >> 6);
    const int nw   = gridDim.x * 4;
    const int d0 = lane << 1;

    const float bg0 = bg[d0], bg1 = bg[d0 + 1];

    if (GH) {
        __half2 w0h[10], w1h[10];
        #pragma unroll
        for (int k2 = 0; k2 < 10; ++k2) {
            w0h[k2] = __floats2half2_rn(Wg[d0 * 20 + 2 * k2], Wg[d0 * 20 + 2 * k2 + 1]);
            w1h[k2] = __floats2half2_rn(Wg[(d0 + 1) * 20 + 2 * k2], Wg[(d0 + 1) * 20 + 2 * k2 + 1]);
        }

        for (int i = wid0; i < N; i += nw) {
            const int beg = off[i], num = cnt[i], end = beg + num;
            float2 acc = *reinterpret_cast<const float2*>(v + (size_t)i * DD + d0);

            int p = beg;
            while (p + 4 <= end) {
                int ee[4], jj[4];
                #pragma unroll
                for (int u = 0; u < 4; ++u) {
                    const int2 pr = spair[p + u];
                    ee[u] = __builtin_amdgcn_readfirstlane(pr.x);
                    jj[u] = __builtin_amdgcn_readfirstlane(pr.y);
                }
                uint32 aa[4];
                float2 gq[4][5];
                #pragma unroll
                for (int u = 0; u < 4; ++u) {
                    aa[u] = *reinterpret_cast<const uint32*>(A + (size_t)jj[u] * DD + d0);
                    const float2* gp = reinterpret_cast<const float2*>(gh + (size_t)ee[u] * 20);
                    #pragma unroll
                    for (int q2 = 0; q2 < 5; ++q2) gq[u][q2] = gp[q2];
                }
                #pragma unroll
                for (int u = 0; u < 4; ++u) {
                    __half2 a0 = __float2half2_rn(0.f), a1 = __float2half2_rn(0.f);
                    #pragma unroll
                    for (int q2 = 0; q2 < 5; ++q2) {
                        const __half2 h0 = __builtin_bit_cast(__half2, gq[u][q2].x);
                        const __half2 h1 = __builtin_bit_cast(__half2, gq[u][q2].y);
                        a0 = __hfma2(h0, w0h[2 * q2], a0);
                        a1 = __hfma2(h0, w1h[2 * q2], a1);
                        a0 = __hfma2(h1, w0h[2 * q2 + 1], a0);
                        a1 = __hfma2(h1, w1h[2 * q2 + 1], a1);
                    }
                    const float t0 = bg0 + __low2float(a0) + __high2float(a0);
                    const float t1 = bg1 + __low2float(a1) + __high2float(a1);
                    union { uint32 u32; float f; } cx, cy;
                    cx.u32 = aa[u] << 16;
                    cy.u32 = aa[u] & 0xffff0000u;
                    acc.x = fmaf(cx.f, t0, acc.x);
                    acc.y = fmaf(cy.f, t1, acc.y);
                }
                p += 4;
            }
            for (; p < end; ++p) {
                const int2 pr = spair[p];
                const int e0 = __builtin_amdgcn_readfirstlane(pr.x);
                const int j0 = __builtin_amdgcn_readfirstlane(pr.y);
                const uint32 a0u = *reinterpret_cast<const uint32*>(A + (size_t)j0 * DD + d0);
                const float2* gp = reinterpret_cast<const float2*>(gh + (size_t)e0 * 20);
                __half2 a0 = __float2half2_rn(0.f), a1 = __float2half2_rn(0.f);
                #pragma unroll
                for (int q2 = 0; q2 < 5; ++q2) {
                    const float2 qq = gp[q2];
                    const __half2 h0 = __builtin_bit_cast(__half2, qq.x);
                    const __half2 h1 = __builtin_bit_cast(__half2, qq.y);
                    a0 = __hfma2(h0, w0h[2 * q2], a0);
                    a1 = __hfma2(h0, w1h[2 * q2], a1);
                    a0 = __hfma2(h1, w0h[2 * q2 + 1], a0);
                    a1 = __hfma2(h1, w1h[2 * q2 + 1], a1);
                }
                const float t0 = bg0 + __low2float(a0) + __high2float(a0);
                const float t1 = bg1 + __low2float(a1) + __high2float(a1);
                union { uint32 u32; float f; } cx, cy;
                cx.u32 = a0u << 16;
                cy.u32 = a0u & 0xffff0000u;
                acc.x = fmaf(cx.f, t0, acc.x);
                acc.y = fmaf(cy.f, t1, acc.y);
            }
            *reinterpret_cast<float2*>(v + (size_t)i * DD + d0) = acc;
        }
    } else {
        // exact R7 f32 body
        float2 wg01[20];
        #pragma unroll
        for (int k = 0; k < 20; ++k) {
            wg01[k].x = Wg[d0 * 20 + k];
            wg01[k].y = Wg[(d0 + 1) * 20 + k];
        }
        for (int i = wid0; i < N; i += nw) {
            const int beg = off[i], num = cnt[i], end = beg + num;
            float2 acc = *reinterpret_cast<const float2*>(v + (size_t)i * DD + d0);
            int p = beg;
            for (; p + 2 <= end; p += 2) {
                const int2 pr0 = spair[p];
                const int2 pr1 = spair[p + 1];
                const int e0 = __builtin_amdgcn_readfirstlane(pr0.x);
                const int j0 = __builtin_amdgcn_readfirstlane(pr0.y);
                const int e1 = __builtin_amdgcn_readfirstlane(pr1.x);
                const int j1 = __builtin_amdgcn_readfirstlane(pr1.y);
                const uint32 a0 = *reinterpret_cast<const uint32*>(A + (size_t)j0 * DD + d0);
                const uint32 a1 = *reinterpret_cast<const uint32*>(A + (size_t)j1 * DD + d0);
                const float4* g0p = reinterpret_cast<const float4*>(g + (size_t)e0 * 20);
                const float4* g1p = reinterpret_cast<const float4*>(g + (size_t)e1 * 20);
                float2 t0 = make_float2(bg0, bg1), t1 = make_float2(bg0, bg1);
                #pragma unroll
                for (int qq = 0; qq < 5; ++qq) {
                    const float4 p0 = g0p[qq];
                    const float4 p1 = g1p[qq];
                    t0.x = fmaf(p0.x, wg01[qq*4+0].x, t0.x); t0.y = fmaf(p0.x, wg01[qq*4+0].y, t0.y);
                    t0.x = fmaf(p0.y, wg01[qq*4+1].x, t0.x); t0.y = fmaf(p0.y, wg01[qq*4+1].y, t0.y);
                    t0.x = fmaf(p0.z, wg01[qq*4+2].x, t0.x); t0.y = fmaf(p0.z, wg01[qq*4+2].y, t0.y);
                    t0.x = fmaf(p0.w, wg01[qq*4+3].x, t0.x); t0.y = fmaf(p0.w, wg01[qq*4+3].y, t0.y);
                    t1.x = fmaf(p1.x, wg01[qq*4+0].x, t1.x); t1.y = fmaf(p1.x, wg01[qq*4+0].y, t1.y);
                    t1.x = fmaf(p1.y, wg01[qq*4+1].x, t1.x); t1.y = fmaf(p1.y, wg01[qq*4+1].y, t1.y);
                    t1.x = fmaf(p1.z, wg01[qq*4+2].x, t1.x); t1.y = fmaf(p1.z, wg01[qq*4+2].y, t1.y);
                    t1.x = fmaf(p1.w, wg01[qq*4+3].x, t1.x); t1.y = fmaf(p1.w, wg01[qq*4+3].y, t1.y);
                }
                union { uint32 u; float f; } c0x, c0y, c1x, c1y;
                c0x.u = a0 << 16; c0y.u = a0 & 0xffff0000u;
                c1x.u = a1 << 16; c1y.u = a1 & 0xffff0000u;
                acc.x = fmaf(c0x.f, t0.x, acc.x); acc.y = fmaf(c0y.f, t0.y, acc.y);
                acc.x = fmaf(c1x.f, t1.x, acc.x); acc.y = fmaf(c1y.f, t1.y, acc.y);
            }
            if (p < end) {
                const int2 pr0 = spair[p];
                const int e0 = __builtin_amdgcn_readfirstlane(pr0.x);
                const int j0 = __builtin_amdgcn_readfirstlane(pr0.y);
                const uint32 a0 = *reinterpret_cast<const uint32*>(A + (size_t)j0 * DD + d0);
                const float4* g0p = reinterpret_cast<const float4*>(g + (size_t)e0 * 20);
                float2 t0 = make_float2(bg0, bg1);
                #pragma unroll
                for (int qq = 0; qq < 5; ++qq) {
                    const float4 p0 = g0p[qq];
                    t0.x = fmaf(p0.x, wg01[qq*4+0].x, t0.x); t0.y = fmaf(p0.x, wg01[qq*4+0].y, t0.y);
                    t0.x = fmaf(p0.y, wg01[qq*4+1].x, t0.x); t0.y = fmaf(p0.y, wg01[qq*4+1].y, t0.y);
                    t0.x = fmaf(p0.z, wg01[qq*4+2].x, t0.x); t0.y = fmaf(p0.z, wg01[qq*4+2].y, t0.y);
                    t0.x = fmaf(p0.w, wg01[qq*4+3].x, t0.x); t0.y = fmaf(p0.w, wg01[qq*4+3].y, t0.y);
                }
                union { uint32 u; float f; } c0x, c0y;
                c0x.u = a0 << 16; c0y.u = a0 & 0xffff0000u;
                acc.x = fmaf(c0x.f, t0.x, acc.x); acc.y = fmaf(c0y.f, t0.y, acc.y);
            }
            *reinterpret_cast<float2*>(v + (size_t)i * DD + d0) = acc;
        }
    }
}

extern "C" void kernel_launch(void* const* d_in, const int* in_sizes, int n_in,
                              void* d_out, int out_size, void* d_ws, size_t ws_size,
                              hipStream_t stream)
{
    const float* x     = (const float*)d_in[0];
    const float* g     = (const float*)d_in[1];
    const int*   idx_i = (const int*)d_in[2];
    const int*   idx_j = (const int*)d_in[3];
    const float* u     = (const float*)d_in[5];
    const float* Wf    = (const float*)d_in[6];
    const float* bf    = (const float*)d_in[7];
    const float* Wg    = (const float*)d_in[8];
    const float* bg    = (const float*)d_in[9];
    const float* Wj    = (const float*)d_in[10];
    const float* bj    = (const float*)d_in[11];
    const float* Wi    = (const float*)d_in[12];
    const float* bi    = (const float*)d_in[13];
    const float* rw1   = (const float*)d_in[14];
    const float* rb1   = (const float*)d_in[15];
    const float* rw2   = (const float*)d_in[16];
    const float* rb2   = (const float*)d_in[17];

    const int N = in_sizes[0] / DD;   // 50000
    const int E = in_sizes[2];        // 640000
    float* out = (float*)d_out;

    // workspace layout
    float*          v     = (float*)d_ws;                           // [N,128] f32
    unsigned short* A     = (unsigned short*)(v + (size_t)N * DD);  // [N,128] bf16
    int*            cnt   = (int*)(A + (size_t)N * DD);
    int*            off   = cnt + N;
    int*            cnt2  = off + N;
    int*            bsum  = cnt2 + N;                               // [64]
    int2*           spair = (int2*)(bsum + 64);                     // [E]
    unsigned short* Wb    = (unsigned short*)(spair + E);           // 9*16384 bf16
    unsigned short* gh    = Wb + 9 * 16384;                         // [E*20] fp16

    const size_t need_gh = (size_t)((char*)(gh + (size_t)E * 20) - (char*)d_ws);
    const bool gh_ok = ws_size >= need_gh;

    dim3 blk(256);
    const int tiles    = (N + 63) / 64;
    const int eblocks  = (E + 255) / 256;
    const int sblocks  = (N + 1023) / 1024;   // 49 for N=50000 (<=64 required)
    const int gchunks  = gh_ok ? (E * 20) / 8 : 0;
    const int gblocks  = gh_ok ? (gchunks + 255) / 256 : 0;

    convert_w<<<72 + gblocks, blk, 0, stream>>>(Wj, Wi, rw1, rw2, Wf, Wb,
                                                g, gh, gchunks);

    hipMemsetAsync(cnt, 0, (size_t)N * sizeof(int), stream);
    hist_kernel<<<eblocks, blk, 0, stream>>>(idx_i, cnt, E);
    scan_reduce<<<sblocks, blk, 0, stream>>>(cnt, bsum, N);
    scan_apply<<<sblocks, blk, 0, stream>>>(cnt, bsum, off, cnt2, N, sblocks);
    scatter_kernel<<<eblocks, blk, 0, stream>>>(idx_i, idx_j, off, cnt2, spair, E);

    dual_gemm<<<tiles, blk, 0, stream>>>(x, Wb, bj, bi, A, v, N);

    if (gh_ok)
        agg_kernel<1><<<2048, blk, 0, stream>>>(off, cnt, spair, gh, g,
                                                Wg, bg, A, v, N);
    else
        agg_kernel<0><<<2048, blk, 0, stream>>>(off, cnt, spair, gh, g,
                                                Wg, bg, A, v, N);

    tail_kernel<<<tiles, blk, 0, stream>>>(v, x, Wb, rb1, rb2, bf, u, out, N);
}

// Round 13
// 244.662 us; speedup vs baseline: 1.0543x; 1.0543x over previous
//
#include <hip/hip_runtime.h>
#include <hip/hip_fp16.h>

#define DD 128

typedef __attribute__((ext_vector_type(8))) short short8;
typedef __attribute__((ext_vector_type(8))) unsigned short ushort8;
typedef __attribute__((ext_vector_type(4))) float floatx4;
typedef unsigned int uint32;

__device__ __forceinline__ float sp(float x) {
    return fmaxf(x, 0.0f) + __logf(1.0f + __expf(-fabsf(x)));
}

__device__ __forceinline__ unsigned short f2bf(float f) {
    union { float f; uint32 u; } c; c.f = f;
    const uint32 u = c.u;
    return (unsigned short)((u + 0x7fffu + ((u >> 16) & 1u)) >> 16);
}

__device__ __forceinline__ unsigned short f2h(float f) {
    __half h = __float2half(f);
    return __builtin_bit_cast(unsigned short, h);
}

// ---------- preconvert ----------
// Weights: f32 [128][128] -> bf16 in MFMA-FRAGMENT ORDER:
//   frag r = (nt*4+kk)*64 + lane  holds  W[nt*16+(lane&15)][((kk*4+(lane>>4))*8 .. +8)]
// Also converts g -> fp16 for agg.
__global__ __launch_bounds__(256)
void convert_w(const float* __restrict__ Wj, const float* __restrict__ Wi,
               const float* __restrict__ rw1, const float* __restrict__ rw2,
               const float* __restrict__ Wf, unsigned short* __restrict__ out,
               const float* __restrict__ g, unsigned short* __restrict__ gh,
               int gchunks)
{
    if ((int)blockIdx.x >= 72) {
        const int gid = ((int)blockIdx.x - 72) * 256 + threadIdx.x;  // 8-float chunk
        if (gid < gchunks) {
            const float4 f0 = reinterpret_cast<const float4*>(g)[2 * gid];
            const float4 f1 = reinterpret_cast<const float4*>(g)[2 * gid + 1];
            ushort8 o;
            o[0] = f2h(f0.x); o[1] = f2h(f0.y); o[2] = f2h(f0.z); o[3] = f2h(f0.w);
            o[4] = f2h(f1.x); o[5] = f2h(f1.y); o[6] = f2h(f1.z); o[7] = f2h(f1.w);
            reinterpret_cast<ushort8*>(gh)[gid] = o;
        }
        return;
    }
    const int gid = blockIdx.x * 256 + threadIdx.x;
    const int mat = gid >> 11;
    const int r   = gid & 2047;
    const int ln  = r & 63;
    const int ntkk = r >> 6;                      // 0..31
    const float* src;
    if      (mat == 0) src = Wj;
    else if (mat == 1) src = Wi;
    else if (mat <= 4) src = rw1 + (size_t)(mat - 2) * 16384;
    else if (mat <= 7) src = rw2 + (size_t)(mat - 5) * 16384;
    else               src = Wf;
    const int row = (ntkk >> 2) * 16 + (ln & 15);
    const int c0  = ((ntkk & 3) * 4 + (ln >> 4)) * 8;
    const float* s = src + row * DD + c0;
    const float4 a = *reinterpret_cast<const float4*>(s);
    const float4 b = *reinterpret_cast<const float4*>(s + 4);
    ushort8 u8;
    u8[0] = f2bf(a.x); u8[1] = f2bf(a.y); u8[2] = f2bf(a.z); u8[3] = f2bf(a.w);
    u8[4] = f2bf(b.x); u8[5] = f2bf(b.y); u8[6] = f2bf(b.z); u8[7] = f2bf(b.w);
    *reinterpret_cast<ushort8*>(out + (size_t)mat * 16384 + (size_t)r * 8) = u8;
}

// linear 32KB copy, 256 threads
__device__ __forceinline__ void stage_wb(const unsigned short* __restrict__ Wb,
                                         unsigned short* wl, int t)
{
    #pragma unroll
    for (int i = 0; i < 8; ++i) {
        const int c = t + i * 256;
        *reinterpret_cast<ushort8*>(wl + c * 8) =
            *reinterpret_cast<const ushort8*>(Wb + c * 8);
    }
}

// linear 32KB copy, 512 threads
__device__ __forceinline__ void stage_wb512(const unsigned short* __restrict__ Wb,
                                            unsigned short* wl, int t)
{
    #pragma unroll
    for (int i = 0; i < 4; ++i) {
        const int c = t + i * 512;
        *reinterpret_cast<ushort8*>(wl + c * 8) =
            *reinterpret_cast<const ushort8*>(Wb + c * 8);
    }
}

__device__ __forceinline__ void load_afrag_act(const float* __restrict__ X,
                                               int m, int q, int n, short8 af[4])
{
    const int mm = m < n ? m : n - 1;
    const float* row = X + (size_t)mm * DD + q * 8;
    #pragma unroll
    for (int kk = 0; kk < 4; ++kk) {
        const float4 a = *reinterpret_cast<const float4*>(row + kk * 32);
        const float4 b = *reinterpret_cast<const float4*>(row + kk * 32 + 4);
        ushort8 u;
        u[0] = f2bf(sp(a.x)); u[1] = f2bf(sp(a.y)); u[2] = f2bf(sp(a.z)); u[3] = f2bf(sp(a.w));
        u[4] = f2bf(sp(b.x)); u[5] = f2bf(sp(b.y)); u[6] = f2bf(sp(b.z)); u[7] = f2bf(sp(b.w));
        af[kk] = __builtin_bit_cast(short8, u);
    }
}

// 16x128 per-wave GEMM; wsrc in frag-order layout (LDS or global)
__device__ __forceinline__ void mfma_gemm(const unsigned short* __restrict__ wsrc,
                                          const short8 af[4], int lane, floatx4 acc[8])
{
    #pragma unroll
    for (int nt = 0; nt < 8; ++nt) {
        #pragma unroll
        for (int kk = 0; kk < 4; ++kk) {
            const short8 bfr = *reinterpret_cast<const short8*>(
                wsrc + (size_t)(((nt * 4 + kk) << 6) + lane) * 8);
            acc[nt] = __builtin_amdgcn_mfma_f32_16x16x32_bf16(af[kk], bfr, acc[nt], 0, 0, 0);
        }
    }
}

// A = act(act(x)@Wj.T+bj) [bf16], v = act(act(x)@Wi.T+bi) [f32]
__global__ __launch_bounds__(256, 4)
void dual_gemm(const float* __restrict__ x,
               const unsigned short* __restrict__ Wb,
               const float* __restrict__ bj, const float* __restrict__ bi,
               unsigned short* __restrict__ Aout, float* __restrict__ vout, int n)
{
    __shared__ __align__(16) unsigned short wl[128 * 128];
    const int t = threadIdx.x;
    const int lane = t & 63, wv = t >> 6;
    const int cl = lane & 15, q = lane >> 4;
    const int m0 = blockIdx.x * 64 + wv * 16;

    short8 af[4];
    load_afrag_act(x, m0 + cl, q, n, af);

    stage_wb(Wb, wl, t);
    __syncthreads();

    floatx4 acc[8];
    #pragma unroll
    for (int nt = 0; nt < 8; ++nt) acc[nt] = (floatx4){0.f, 0.f, 0.f, 0.f};
    mfma_gemm(wl, af, lane, acc);

    #pragma unroll
    for (int nt = 0; nt < 8; ++nt) {
        const int col = nt * 16 + cl;
        const float bb = bj[col];
        #pragma unroll
        for (int r = 0; r < 4; ++r) {
            const int row = m0 + q * 4 + r;
            if (row < n) Aout[(size_t)row * DD + col] = f2bf(sp(acc[nt][r] + bb));
        }
    }

    __syncthreads();
    stage_wb(Wb + 16384, wl, t);
    __syncthreads();

    #pragma unroll
    for (int nt = 0; nt < 8; ++nt) acc[nt] = (floatx4){0.f, 0.f, 0.f, 0.f};
    mfma_gemm(wl, af, lane, acc);

    #pragma unroll
    for (int nt = 0; nt < 8; ++nt) {
        const int col = nt * 16 + cl;
        const float bb = bi[col];
        #pragma unroll
        for (int r = 0; r < 4; ++r) {
            const int row = m0 + q * 4 + r;
            if (row < n) vout[(size_t)row * DD + col] = sp(acc[nt][r] + bb);
        }
    }
}

// fused tail: 3 residual layers + final output.
// 512 threads / 8 waves / 128 rows per block. LDS = wl 32K + hl 32K = 64K
// -> 2 blocks/CU = 16 waves/CU (2x R9). R9-proven serial staging; R11-proven
// direct-global vac loads; fused residual C-in.
__global__ __launch_bounds__(512, 4)
void tail_kernel(const float* __restrict__ vin, const float* __restrict__ x,
                 const unsigned short* __restrict__ Wb,
                 const float* __restrict__ rb1, const float* __restrict__ rb2,
                 const float* __restrict__ bf, const float* __restrict__ u,
                 float* __restrict__ out, int n)
{
    __shared__ __align__(16) unsigned short wl[128 * 128];   // 32 KB
    __shared__ __align__(16) unsigned short hl[128 * 128];   // 32 KB
    const int t = threadIdx.x;
    const int lane = t & 63, wv = t >> 6;       // wv 0..7
    const int cl = lane & 15, q = lane >> 4;
    const int mb = blockIdx.x * 128;
    const int ml2 = wv * 16 + cl;

    // v accumulator direct from global (D-layout; L2/L3-resident)
    floatx4 vac[8];
    #pragma unroll
    for (int nt = 0; nt < 8; ++nt) {
        #pragma unroll
        for (int r = 0; r < 4; ++r) {
            const int row = mb + wv * 16 + q * 4 + r;
            const int col = nt * 16 + cl;
            vac[nt][r] = (row < n) ? vin[(size_t)row * DD + col] : 0.f;
        }
    }

    // layer-0 A-fragments straight from global vin
    short8 af[4];
    load_afrag_act(vin, mb + wv * 16 + cl, q, n, af);

    stage_wb512(Wb + 2 * 16384, wl, t);    // W1_0
    __syncthreads();

    #pragma unroll
    for (int l = 0; l < 3; ++l) {
        if (l > 0) {
            // af = bf16(sp(vac)) via per-wave hl bounce (same-wave LDS, ordered)
            #pragma unroll
            for (int nt = 0; nt < 8; ++nt) {
                const int col = nt * 16 + cl;
                const int ch = col >> 3;
                #pragma unroll
                for (int r = 0; r < 4; ++r) {
                    const int ml = wv * 16 + q * 4 + r;
                    hl[ml * 128 + ((ch ^ (ml & 15)) << 3) + (col & 7)] = f2bf(sp(vac[nt][r]));
                }
            }
            #pragma unroll
            for (int kk = 0; kk < 4; ++kk)
                af[kk] = *reinterpret_cast<const short8*>(hl + ml2 * 128 + (((kk * 4 + q) ^ cl) << 3));
        }

        floatx4 acc[8];
        #pragma unroll
        for (int nt = 0; nt < 8; ++nt) acc[nt] = (floatx4){0.f, 0.f, 0.f, 0.f};
        mfma_gemm(wl, af, lane, acc);

        // h2 = act(acc + b1) -> hl, then second A-fragments
        const float* b1 = rb1 + (size_t)l * DD;
        #pragma unroll
        for (int nt = 0; nt < 8; ++nt) {
            const int col = nt * 16 + cl;
            const int ch = col >> 3;
            const float bb = b1[col];
            #pragma unroll
            for (int r = 0; r < 4; ++r) {
                const int ml = wv * 16 + q * 4 + r;
                hl[ml * 128 + ((ch ^ (ml & 15)) << 3) + (col & 7)] = f2bf(sp(acc[nt][r] + bb));
            }
        }
        short8 af2[4];
        #pragma unroll
        for (int kk = 0; kk < 4; ++kk)
            af2[kk] = *reinterpret_cast<const short8*>(hl + ml2 * 128 + (((kk * 4 + q) ^ cl) << 3));

        __syncthreads();                           // all waves done with W1_l
        stage_wb512(Wb + (size_t)(5 + l) * 16384, wl, t);
        __syncthreads();                           // wl = W2_l

        // second GEMM accumulates directly into vac (residual add fused)
        mfma_gemm(wl, af2, lane, vac);
        const float* b2 = rb2 + (size_t)l * DD;
        #pragma unroll
        for (int nt = 0; nt < 8; ++nt) {
            const float bb = b2[nt * 16 + cl];
            #pragma unroll
            for (int r = 0; r < 4; ++r) vac[nt][r] += bb;
        }

        __syncthreads();                           // all waves done with W2_l
        const int nxt = (l < 2) ? (3 + l) : 8;     // next W1, or Wf
        stage_wb512(Wb + (size_t)nxt * 16384, wl, t);
        __syncthreads();                           // wl = next weight
    }

    // wl holds Wf
    #pragma unroll
    for (int nt = 0; nt < 8; ++nt) {
        const int col = nt * 16 + cl;
        const int ch = col >> 3;
        #pragma unroll
        for (int r = 0; r < 4; ++r) {
            const int ml = wv * 16 + q * 4 + r;
            hl[ml * 128 + ((ch ^ (ml & 15)) << 3) + (col & 7)] = f2bf(sp(vac[nt][r]));
        }
    }
    short8 aff[4];
    #pragma unroll
    for (int kk = 0; kk < 4; ++kk)
        aff[kk] = *reinterpret_cast<const short8*>(hl + ml2 * 128 + (((kk * 4 + q) ^ cl) << 3));

    floatx4 acc[8];
    #pragma unroll
    for (int nt = 0; nt < 8; ++nt) acc[nt] = (floatx4){0.f, 0.f, 0.f, 0.f};
    mfma_gemm(wl, aff, lane, acc);

    #pragma unroll
    for (int nt = 0; nt < 8; ++nt) {
        const int col = nt * 16 + cl;
        const float bb = bf[col];
        const float uu = u[col];
        #pragma unroll
        for (int r = 0; r < 4; ++r) {
            const int row = mb + wv * 16 + q * 4 + r;
            if (row < n)
                out[(size_t)row * DD + col] =
                    acc[nt][r] + bb + uu * x[(size_t)row * DD + col];
        }
    }
}

// ---------- CSR build ----------

__global__ __launch_bounds__(256)
void hist_kernel(const int* __restrict__ idx_i, int* __restrict__ cnt, int E)
{
    const int e = blockIdx.x * 256 + threadIdx.x;
    if (e < E) atomicAdd(&cnt[idx_i[e]], 1);
}

__global__ __launch_bounds__(256)
void scan_reduce(const int* __restrict__ cnt, int* __restrict__ bsum, int n)
{
    __shared__ int wsum[4];
    const int t = threadIdx.x;
    const int lane = t & 63, wv = t >> 6;
    const int i0 = blockIdx.x * 1024 + t * 4;
    int s = 0;
    #pragma unroll
    for (int k = 0; k < 4; ++k) if (i0 + k < n) s += cnt[i0 + k];
    #pragma unroll
    for (int d = 1; d < 64; d <<= 1) s += __shfl_down(s, d, 64);
    if (lane == 0) wsum[wv] = s;
    __syncthreads();
    if (t == 0) bsum[blockIdx.x] = wsum[0] + wsum[1] + wsum[2] + wsum[3];
}

// local exclusive scan + block offset (bsum scanned in-kernel); zeroes cnt2
__global__ __launch_bounds__(256)
void scan_apply(const int* __restrict__ cnt, const int* __restrict__ bsum,
                int* __restrict__ off, int* __restrict__ cnt2, int n, int nb)
{
    __shared__ int wsum[4];
    const int t = threadIdx.x;
    const int lane = t & 63, wv = t >> 6;

    int bval = (lane < nb && lane < (int)blockIdx.x) ? bsum[lane] : 0;
    #pragma unroll
    for (int d = 32; d >= 1; d >>= 1) bval += __shfl_down(bval, d, 64);
    const int blk_off = __shfl(bval, 0, 64);

    const int i0 = blockIdx.x * 1024 + t * 4;
    const int v0 = (i0 + 0 < n) ? cnt[i0 + 0] : 0;
    const int v1 = (i0 + 1 < n) ? cnt[i0 + 1] : 0;
    const int v2 = (i0 + 2 < n) ? cnt[i0 + 2] : 0;
    const int v3 = (i0 + 3 < n) ? cnt[i0 + 3] : 0;
    const int s = v0 + v1 + v2 + v3;
    int incl = s;
    #pragma unroll
    for (int d = 1; d < 64; d <<= 1) {
        const int y = __shfl_up(incl, d, 64);
        if (lane >= d) incl += y;
    }
    if (lane == 63) wsum[wv] = incl;
    __syncthreads();
    int woff = blk_off;
    #pragma unroll
    for (int w = 0; w < 4; ++w) if (w < wv) woff += wsum[w];
    const int excl = woff + incl - s;
    if (i0 + 0 < n) { off[i0 + 0] = excl;                cnt2[i0 + 0] = 0; }
    if (i0 + 1 < n) { off[i0 + 1] = excl + v0;           cnt2[i0 + 1] = 0; }
    if (i0 + 2 < n) { off[i0 + 2] = excl + v0 + v1;      cnt2[i0 + 2] = 0; }
    if (i0 + 3 < n) { off[i0 + 3] = excl + v0 + v1 + v2; cnt2[i0 + 3] = 0; }
}

__global__ __launch_bounds__(256)
void scatter_kernel(const int* __restrict__ idx_i, const int* __restrict__ idx_j,
                    const int* __restrict__ off, int* __restrict__ cnt2,
                    int2* __restrict__ spair, int E)
{
    const int e = blockIdx.x * 256 + threadIdx.x;
    if (e < E) {
        const int i = idx_i[e];
        const int p = off[i] + atomicAdd(&cnt2[i], 1);
        spair[p] = make_int2(e, idx_j[e]);
    }
}

// grid-stride waves over atoms; R4/R7-proven load structure.
// GH=1: fp16-packed gate math reading preconverted g-half rows.
// GH=0: exact R7 f32 body (fallback).
template<int GH>
__global__ __launch_bounds__(256, 4)
void agg_kernel(const int* __restrict__ off, const int* __restrict__ cnt,
                const int2* __restrict__ spair,
                const unsigned short* __restrict__ gh,
                const float* __restrict__ g,
                const float* __restrict__ Wg, const float* __restrict__ bg,
                const unsigned short* __restrict__ A, float* __restrict__ v, int N)
{
    const int t = threadIdx.x;
    const int lane = t & 63;
    const int wid0 = blockIdx.x * 4 + (t >> 6);
    const int nw   = gridDim.x * 4;
    const int d0 = lane << 1;

    const float bg0 = bg[d0], bg1 = bg[d0 + 1];

    if (GH) {
        __half2 w0h[10], w1h[10];
        #pragma unroll
        for (int k2 = 0; k2 < 10; ++k2) {
            w0h[k2] = __floats2half2_rn(Wg[d0 * 20 + 2 * k2], Wg[d0 * 20 + 2 * k2 + 1]);
            w1h[k2] = __floats2half2_rn(Wg[(d0 + 1) * 20 + 2 * k2], Wg[(d0 + 1) * 20 + 2 * k2 + 1]);
        }

        for (int i = wid0; i < N; i += nw) {
            const int beg = off[i], num = cnt[i], end = beg + num;
            float2 acc = *reinterpret_cast<const float2*>(v + (size_t)i * DD + d0);

            int p = beg;
            while (p + 4 <= end) {
                int ee[4], jj[4];
                #pragma unroll
                for (int u = 0; u < 4; ++u) {
                    const int2 pr = spair[p + u];
                    ee[u] = __builtin_amdgcn_readfirstlane(pr.x);
                    jj[u] = __builtin_amdgcn_readfirstlane(pr.y);
                }
                uint32 aa[4];
                float2 gq[4][5];
                #pragma unroll
                for (int u = 0; u < 4; ++u) {
                    aa[u] = *reinterpret_cast<const uint32*>(A + (size_t)jj[u] * DD + d0);
                    const float2* gp = reinterpret_cast<const float2*>(gh + (size_t)ee[u] * 20);
                    #pragma unroll
                    for (int q2 = 0; q2 < 5; ++q2) gq[u][q2] = gp[q2];
                }
                #pragma unroll
                for (int u = 0; u < 4; ++u) {
                    __half2 a0 = __float2half2_rn(0.f), a1 = __float2half2_rn(0.f);
                    #pragma unroll
                    for (int q2 = 0; q2 < 5; ++q2) {
                        const __half2 h0 = __builtin_bit_cast(__half2, gq[u][q2].x);
                        const __half2 h1 = __builtin_bit_cast(__half2, gq[u][q2].y);
                        a0 = __hfma2(h0, w0h[2 * q2], a0);
                        a1 = __hfma2(h0, w1h[2 * q2], a1);
                        a0 = __hfma2(h1, w0h[2 * q2 + 1], a0);
                        a1 = __hfma2(h1, w1h[2 * q2 + 1], a1);
                    }
                    const float t0 = bg0 + __low2float(a0) + __high2float(a0);
                    const float t1 = bg1 + __low2float(a1) + __high2float(a1);
                    union { uint32 u32; float f; } cx, cy;
                    cx.u32 = aa[u] << 16;
                    cy.u32 = aa[u] & 0xffff0000u;
                    acc.x = fmaf(cx.f, t0, acc.x);
                    acc.y = fmaf(cy.f, t1, acc.y);
                }
                p += 4;
            }
            for (; p < end; ++p) {
                const int2 pr = spair[p];
                const int e0 = __builtin_amdgcn_readfirstlane(pr.x);
                const int j0 = __builtin_amdgcn_readfirstlane(pr.y);
                const uint32 a0u = *reinterpret_cast<const uint32*>(A + (size_t)j0 * DD + d0);
                const float2* gp = reinterpret_cast<const float2*>(gh + (size_t)e0 * 20);
                __half2 a0 = __float2half2_rn(0.f), a1 = __float2half2_rn(0.f);
                #pragma unroll
                for (int q2 = 0; q2 < 5; ++q2) {
                    const float2 qq = gp[q2];
                    const __half2 h0 = __builtin_bit_cast(__half2, qq.x);
                    const __half2 h1 = __builtin_bit_cast(__half2, qq.y);
                    a0 = __hfma2(h0, w0h[2 * q2], a0);
                    a1 = __hfma2(h0, w1h[2 * q2], a1);
                    a0 = __hfma2(h1, w0h[2 * q2 + 1], a0);
                    a1 = __hfma2(h1, w1h[2 * q2 + 1], a1);
                }
                const float t0 = bg0 + __low2float(a0) + __high2float(a0);
                const float t1 = bg1 + __low2float(a1) + __high2float(a1);
                union { uint32 u32; float f; } cx, cy;
                cx.u32 = a0u << 16;
                cy.u32 = a0u & 0xffff0000u;
                acc.x = fmaf(cx.f, t0, acc.x);
                acc.y = fmaf(cy.f, t1, acc.y);
            }
            *reinterpret_cast<float2*>(v + (size_t)i * DD + d0) = acc;
        }
    } else {
        // exact R7 f32 body
        float2 wg01[20];
        #pragma unroll
        for (int k = 0; k < 20; ++k) {
            wg01[k].x = Wg[d0 * 20 + k];
            wg01[k].y = Wg[(d0 + 1) * 20 + k];
        }
        for (int i = wid0; i < N; i += nw) {
            const int beg = off[i], num = cnt[i], end = beg + num;
            float2 acc = *reinterpret_cast<const float2*>(v + (size_t)i * DD + d0);
            int p = beg;
            for (; p + 2 <= end; p += 2) {
                const int2 pr0 = spair[p];
                const int2 pr1 = spair[p + 1];
                const int e0 = __builtin_amdgcn_readfirstlane(pr0.x);
                const int j0 = __builtin_amdgcn_readfirstlane(pr0.y);
                const int e1 = __builtin_amdgcn_readfirstlane(pr1.x);
                const int j1 = __builtin_amdgcn_readfirstlane(pr1.y);
                const uint32 a0 = *reinterpret_cast<const uint32*>(A + (size_t)j0 * DD + d0);
                const uint32 a1 = *reinterpret_cast<const uint32*>(A + (size_t)j1 * DD + d0);
                const float4* g0p = reinterpret_cast<const float4*>(g + (size_t)e0 * 20);
                const float4* g1p = reinterpret_cast<const float4*>(g + (size_t)e1 * 20);
                float2 t0 = make_float2(bg0, bg1), t1 = make_float2(bg0, bg1);
                #pragma unroll
                for (int qq = 0; qq < 5; ++qq) {
                    const float4 p0 = g0p[qq];
                    const float4 p1 = g1p[qq];
                    t0.x = fmaf(p0.x, wg01[qq*4+0].x, t0.x); t0.y = fmaf(p0.x, wg01[qq*4+0].y, t0.y);
                    t0.x = fmaf(p0.y, wg01[qq*4+1].x, t0.x); t0.y = fmaf(p0.y, wg01[qq*4+1].y, t0.y);
                    t0.x = fmaf(p0.z, wg01[qq*4+2].x, t0.x); t0.y = fmaf(p0.z, wg01[qq*4+2].y, t0.y);
                    t0.x = fmaf(p0.w, wg01[qq*4+3].x, t0.x); t0.y = fmaf(p0.w, wg01[qq*4+3].y, t0.y);
                    t1.x = fmaf(p1.x, wg01[qq*4+0].x, t1.x); t1.y = fmaf(p1.x, wg01[qq*4+0].y, t1.y);
                    t1.x = fmaf(p1.y, wg01[qq*4+1].x, t1.x); t1.y = fmaf(p1.y, wg01[qq*4+1].y, t1.y);
                    t1.x = fmaf(p1.z, wg01[qq*4+2].x, t1.x); t1.y = fmaf(p1.z, wg01[qq*4+2].y, t1.y);
                    t1.x = fmaf(p1.w, wg01[qq*4+3].x, t1.x); t1.y = fmaf(p1.w, wg01[qq*4+3].y, t1.y);
                }
                union { uint32 u; float f; } c0x, c0y, c1x, c1y;
                c0x.u = a0 << 16; c0y.u = a0 & 0xffff0000u;
                c1x.u = a1 << 16; c1y.u = a1 & 0xffff0000u;
                acc.x = fmaf(c0x.f, t0.x, acc.x); acc.y = fmaf(c0y.f, t0.y, acc.y);
                acc.x = fmaf(c1x.f, t1.x, acc.x); acc.y = fmaf(c1y.f, t1.y, acc.y);
            }
            if (p < end) {
                const int2 pr0 = spair[p];
                const int e0 = __builtin_amdgcn_readfirstlane(pr0.x);
                const int j0 = __builtin_amdgcn_readfirstlane(pr0.y);
                const uint32 a0 = *reinterpret_cast<const uint32*>(A + (size_t)j0 * DD + d0);
                const float4* g0p = reinterpret_cast<const float4*>(g + (size_t)e0 * 20);
                float2 t0 = make_float2(bg0, bg1);
                #pragma unroll
                for (int qq = 0; qq < 5; ++qq) {
                    const float4 p0 = g0p[qq];
                    t0.x = fmaf(p0.x, wg01[qq*4+0].x, t0.x); t0.y = fmaf(p0.x, wg01[qq*4+0].y, t0.y);
                    t0.x = fmaf(p0.y, wg01[qq*4+1].x, t0.x); t0.y = fmaf(p0.y, wg01[qq*4+1].y, t0.y);
                    t0.x = fmaf(p0.z, wg01[qq*4+2].x, t0.x); t0.y = fmaf(p0.z, wg01[qq*4+2].y, t0.y);
                    t0.x = fmaf(p0.w, wg01[qq*4+3].x, t0.x); t0.y = fmaf(p0.w, wg01[qq*4+3].y, t0.y);
                }
                union { uint32 u; float f; } c0x, c0y;
                c0x.u = a0 << 16; c0y.u = a0 & 0xffff0000u;
                acc.x = fmaf(c0x.f, t0.x, acc.x); acc.y = fmaf(c0y.f, t0.y, acc.y);
            }
            *reinterpret_cast<float2*>(v + (size_t)i * DD + d0) = acc;
        }
    }
}

extern "C" void kernel_launch(void* const* d_in, const int* in_sizes, int n_in,
                              void* d_out, int out_size, void* d_ws, size_t ws_size,
                              hipStream_t stream)
{
    const float* x     = (const float*)d_in[0];
    const float* g     = (const float*)d_in[1];
    const int*   idx_i = (const int*)d_in[2];
    const int*   idx_j = (const int*)d_in[3];
    const float* u     = (const float*)d_in[5];
    const float* Wf    = (const float*)d_in[6];
    const float* bf    = (const float*)d_in[7];
    const float* Wg    = (const float*)d_in[8];
    const float* bg    = (const float*)d_in[9];
    const float* Wj    = (const float*)d_in[10];
    const float* bj    = (const float*)d_in[11];
    const float* Wi    = (const float*)d_in[12];
    const float* bi    = (const float*)d_in[13];
    const float* rw1   = (const float*)d_in[14];
    const float* rb1   = (const float*)d_in[15];
    const float* rw2   = (const float*)d_in[16];
    const float* rb2   = (const float*)d_in[17];

    const int N = in_sizes[0] / DD;   // 50000
    const int E = in_sizes[2];        // 640000
    float* out = (float*)d_out;

    // workspace layout
    float*          v     = (float*)d_ws;                           // [N,128] f32
    unsigned short* A     = (unsigned short*)(v + (size_t)N * DD);  // [N,128] bf16
    int*            cnt   = (int*)(A + (size_t)N * DD);
    int*            off   = cnt + N;
    int*            cnt2  = off + N;
    int*            bsum  = cnt2 + N;                               // [64]
    int2*           spair = (int2*)(bsum + 64);                     // [E]
    unsigned short* Wb    = (unsigned short*)(spair + E);           // 9*16384 bf16
    unsigned short* gh    = Wb + 9 * 16384;                         // [E*20] fp16

    const size_t need_gh = (size_t)((char*)(gh + (size_t)E * 20) - (char*)d_ws);
    const bool gh_ok = ws_size >= need_gh;

    dim3 blk(256);
    const int tiles    = (N + 63) / 64;
    const int ttiles   = (N + 127) / 128;     // tail: 128 rows/block
    const int eblocks  = (E + 255) / 256;
    const int sblocks  = (N + 1023) / 1024;   // 49 for N=50000 (<=64 required)
    const int gchunks  = gh_ok ? (E * 20) / 8 : 0;
    const int gblocks  = gh_ok ? (gchunks + 255) / 256 : 0;

    convert_w<<<72 + gblocks, blk, 0, stream>>>(Wj, Wi, rw1, rw2, Wf, Wb,
                                                g, gh, gchunks);

    hipMemsetAsync(cnt, 0, (size_t)N * sizeof(int), stream);
    hist_kernel<<<eblocks, blk, 0, stream>>>(idx_i, cnt, E);
    scan_reduce<<<sblocks, blk, 0, stream>>>(cnt, bsum, N);
    scan_apply<<<sblocks, blk, 0, stream>>>(cnt, bsum, off, cnt2, N, sblocks);
    scatter_kernel<<<eblocks, blk, 0, stream>>>(idx_i, idx_j, off, cnt2, spair, E);

    dual_gemm<<<tiles, blk, 0, stream>>>(x, Wb, bj, bi, A, v, N);

    if (gh_ok)
        agg_kernel<1><<<2048, blk, 0, stream>>>(off, cnt, spair, gh, g,
                                                Wg, bg, A, v, N);
    else
        agg_kernel<0><<<2048, blk, 0, stream>>>(off, cnt, spair, gh, g,
                                                Wg, bg, A, v, N);

    tail_kernel<<<ttiles, dim3(512), 0, stream>>>(v, x, Wb, rb1, rb2, bf, u, out, N);
}

// Round 14
// 241.797 us; speedup vs baseline: 1.0668x; 1.0118x over previous
//
#include <hip/hip_runtime.h>
#include <hip/hip_fp16.h>

#define DD 128

typedef __attribute__((ext_vector_type(8))) short short8;
typedef __attribute__((ext_vector_type(8))) unsigned short ushort8;
typedef __attribute__((ext_vector_type(4))) float floatx4;
typedef unsigned int uint32;

__device__ __forceinline__ float sp(float x) {
    return fmaxf(x, 0.0f) + __logf(1.0f + __expf(-fabsf(x)));
}

__device__ __forceinline__ unsigned short f2bf(float f) {
    union { float f; uint32 u; } c; c.f = f;
    const uint32 u = c.u;
    return (unsigned short)((u + 0x7fffu + ((u >> 16) & 1u)) >> 16);
}

__device__ __forceinline__ unsigned short f2h(float f) {
    __half h = __float2half(f);
    return __builtin_bit_cast(unsigned short, h);
}

// ---------- fused prep: weights f32->bf16 (row-major, 16B-chunk XOR swizzle),
// g f32->fp16, and the idx_i histogram — all independent, one launch ----------
__global__ __launch_bounds__(256)
void prep_kernel(const float* __restrict__ Wj, const float* __restrict__ Wi,
                 const float* __restrict__ rw1, const float* __restrict__ rw2,
                 const float* __restrict__ Wf, unsigned short* __restrict__ out,
                 const float* __restrict__ g, unsigned short* __restrict__ gh,
                 int gchunks, int gh_blocks,
                 const int* __restrict__ idx_i, int* __restrict__ cnt, int E)
{
    const int b = (int)blockIdx.x;
    if (b >= 72 + gh_blocks) {
        // histogram
        const int e = (b - 72 - gh_blocks) * 256 + threadIdx.x;
        if (e < E) atomicAdd(&cnt[idx_i[e]], 1);
        return;
    }
    if (b >= 72) {
        const int gid = (b - 72) * 256 + threadIdx.x;  // 8-float chunk
        if (gid < gchunks) {
            const float4 f0 = reinterpret_cast<const float4*>(g)[2 * gid];
            const float4 f1 = reinterpret_cast<const float4*>(g)[2 * gid + 1];
            ushort8 o;
            o[0] = f2h(f0.x); o[1] = f2h(f0.y); o[2] = f2h(f0.z); o[3] = f2h(f0.w);
            o[4] = f2h(f1.x); o[5] = f2h(f1.y); o[6] = f2h(f1.z); o[7] = f2h(f1.w);
            reinterpret_cast<ushort8*>(gh)[gid] = o;
        }
        return;
    }
    const int gid = b * 256 + threadIdx.x;   // 8-float chunk id
    const int mat = gid >> 11;
    const int f8  = gid & 2047;
    const float* src;
    if      (mat == 0) src = Wj;
    else if (mat == 1) src = Wi;
    else if (mat <= 4) src = rw1 + (size_t)(mat - 2) * 16384;
    else if (mat <= 7) src = rw2 + (size_t)(mat - 5) * 16384;
    else               src = Wf;
    const int row = f8 >> 4;
    const int ch  = f8 & 15;
    const float4 a = reinterpret_cast<const float4*>(src)[2 * f8];
    const float4 bb = reinterpret_cast<const float4*>(src)[2 * f8 + 1];
    ushort8 u8;
    u8[0] = f2bf(a.x); u8[1] = f2bf(a.y); u8[2] = f2bf(a.z); u8[3] = f2bf(a.w);
    u8[4] = f2bf(bb.x); u8[5] = f2bf(bb.y); u8[6] = f2bf(bb.z); u8[7] = f2bf(bb.w);
    *reinterpret_cast<ushort8*>(out + (size_t)mat * 16384 + row * 128 +
                                ((ch ^ (row & 15)) << 3)) = u8;
}

__device__ __forceinline__ void stage_wb(const unsigned short* __restrict__ Wb,
                                         unsigned short* wl, int t)
{
    #pragma unroll
    for (int i = 0; i < 8; ++i) {
        const int c = t + i * 256;
        *reinterpret_cast<ushort8*>(wl + c * 8) =
            *reinterpret_cast<const ushort8*>(Wb + c * 8);
    }
}

__device__ __forceinline__ void load_afrag_act(const float* __restrict__ X,
                                               int m, int q, int n, short8 af[4])
{
    const int mm = m < n ? m : n - 1;
    const float* row = X + (size_t)mm * DD + q * 8;
    #pragma unroll
    for (int kk = 0; kk < 4; ++kk) {
        const float4 a = *reinterpret_cast<const float4*>(row + kk * 32);
        const float4 b = *reinterpret_cast<const float4*>(row + kk * 32 + 4);
        ushort8 u;
        u[0] = f2bf(sp(a.x)); u[1] = f2bf(sp(a.y)); u[2] = f2bf(sp(a.z)); u[3] = f2bf(sp(a.w));
        u[4] = f2bf(sp(b.x)); u[5] = f2bf(sp(b.y)); u[6] = f2bf(sp(b.z)); u[7] = f2bf(sp(b.w));
        af[kk] = __builtin_bit_cast(short8, u);
    }
}

__device__ __forceinline__ void mfma_gemm(const unsigned short* wl,
                                          const short8 af[4],
                                          int cl, int q, floatx4 acc[8])
{
    #pragma unroll
    for (int nt = 0; nt < 8; ++nt) {
        const int nrow = nt * 16 + cl;
        #pragma unroll
        for (int kk = 0; kk < 4; ++kk) {
            const int chs = (kk * 4 + q) ^ cl;
            const short8 bfr = *reinterpret_cast<const short8*>(wl + nrow * 128 + (chs << 3));
            acc[nt] = __builtin_amdgcn_mfma_f32_16x16x32_bf16(af[kk], bfr, acc[nt], 0, 0, 0);
        }
    }
}

// fused scatter + dual_gemm (independent work, one launch, blockIdx routing)
__global__ __launch_bounds__(256, 4)
void scatter_dual(const int* __restrict__ idx_i, const int* __restrict__ idx_j,
                  const int* __restrict__ off, int* __restrict__ cnt2,
                  int2* __restrict__ spair, int E, int eblocks,
                  const float* __restrict__ x,
                  const unsigned short* __restrict__ Wb,
                  const float* __restrict__ bj, const float* __restrict__ bi,
                  unsigned short* __restrict__ Aout, float* __restrict__ vout, int n)
{
    __shared__ __align__(16) unsigned short wl[128 * 128];
    const int t = threadIdx.x;

    if ((int)blockIdx.x < eblocks) {
        // ---- scatter ----
        const int e = blockIdx.x * 256 + t;
        if (e < E) {
            const int i = idx_i[e];
            const int p = off[i] + atomicAdd(&cnt2[i], 1);
            spair[p] = make_int2(e, idx_j[e]);
        }
        return;
    }

    // ---- dual_gemm ----
    const int bid = (int)blockIdx.x - eblocks;
    const int lane = t & 63, wv = t >> 6;
    const int cl = lane & 15, q = lane >> 4;
    const int m0 = bid * 64 + wv * 16;

    short8 af[4];
    load_afrag_act(x, m0 + cl, q, n, af);

    stage_wb(Wb, wl, t);
    __syncthreads();

    floatx4 acc[8];
    #pragma unroll
    for (int nt = 0; nt < 8; ++nt) acc[nt] = (floatx4){0.f, 0.f, 0.f, 0.f};
    mfma_gemm(wl, af, cl, q, acc);

    #pragma unroll
    for (int nt = 0; nt < 8; ++nt) {
        const int col = nt * 16 + cl;
        const float bb = bj[col];
        #pragma unroll
        for (int r = 0; r < 4; ++r) {
            const int row = m0 + q * 4 + r;
            if (row < n) Aout[(size_t)row * DD + col] = f2bf(sp(acc[nt][r] + bb));
        }
    }

    __syncthreads();
    stage_wb(Wb + 16384, wl, t);
    __syncthreads();

    #pragma unroll
    for (int nt = 0; nt < 8; ++nt) acc[nt] = (floatx4){0.f, 0.f, 0.f, 0.f};
    mfma_gemm(wl, af, cl, q, acc);

    #pragma unroll
    for (int nt = 0; nt < 8; ++nt) {
        const int col = nt * 16 + cl;
        const float bb = bi[col];
        #pragma unroll
        for (int r = 0; r < 4; ++r) {
            const int row = m0 + q * 4 + r;
            if (row < n) vout[(size_t)row * DD + col] = sp(acc[nt][r] + bb);
        }
    }
}

// fused tail (best-known 74us variant): 3 residual layers + final output,
// v kept in registers; vt+hl+wl = 80KB LDS, serial 2-barrier staging.
__global__ __launch_bounds__(256, 2)
void tail_kernel(const float* __restrict__ vin, const float* __restrict__ x,
                 const unsigned short* __restrict__ Wb,
                 const float* __restrict__ rb1, const float* __restrict__ rb2,
                 const float* __restrict__ bf, const float* __restrict__ u,
                 float* __restrict__ out, int n)
{
    __shared__ __align__(16) unsigned short wl[128 * 128];
    __shared__ __align__(16) unsigned short hl[64 * 128];
    __shared__ __align__(16) float vt[64 * 128];
    const int t = threadIdx.x;
    const int lane = t & 63, wv = t >> 6;
    const int cl = lane & 15, q = lane >> 4;
    const int mb = blockIdx.x * 64;

    #pragma unroll
    for (int i = 0; i < 8; ++i) {
        const int c = t + i * 256;
        const int row = c >> 5;
        const int chv = c & 31;
        float4 val = make_float4(0.f, 0.f, 0.f, 0.f);
        if (mb + row < n) val = reinterpret_cast<const float4*>(vin)[(size_t)mb * 32 + c];
        *reinterpret_cast<float4*>(vt + row * 128 + ((chv ^ (row & 15)) << 2)) = val;
    }
    stage_wb(Wb + 2 * 16384, wl, t);
    __syncthreads();

    floatx4 vac[8];
    #pragma unroll
    for (int nt = 0; nt < 8; ++nt) {
        #pragma unroll
        for (int r = 0; r < 4; ++r) {
            const int rl = wv * 16 + q * 4 + r;
            const int col = nt * 16 + cl;
            const int chv = col >> 2;
            vac[nt][r] = vt[rl * 128 + ((chv ^ (rl & 15)) << 2) + (col & 3)];
        }
    }

    short8 af[4];
    {
        const int rl = wv * 16 + cl;
        #pragma unroll
        for (int kk = 0; kk < 4; ++kk) {
            const int c0 = q * 2 + kk * 8;
            const floatx4 A0 = *reinterpret_cast<const floatx4*>(vt + rl * 128 + (((c0    ) ^ cl) << 2));
            const floatx4 A1 = *reinterpret_cast<const floatx4*>(vt + rl * 128 + (((c0 + 1) ^ cl) << 2));
            ushort8 u8;
            u8[0] = f2bf(sp(A0[0])); u8[1] = f2bf(sp(A0[1])); u8[2] = f2bf(sp(A0[2])); u8[3] = f2bf(sp(A0[3]));
            u8[4] = f2bf(sp(A1[0])); u8[5] = f2bf(sp(A1[1])); u8[6] = f2bf(sp(A1[2])); u8[7] = f2bf(sp(A1[3]));
            af[kk] = __builtin_bit_cast(short8, u8);
        }
    }

    const int ml2 = wv * 16 + cl;

    for (int l = 0; l < 3; ++l) {
        if (l > 0) {
            #pragma unroll
            for (int nt = 0; nt < 8; ++nt) {
                const int col = nt * 16 + cl;
                const int ch = col >> 3;
                #pragma unroll
                for (int r = 0; r < 4; ++r) {
                    const int ml = wv * 16 + q * 4 + r;
                    hl[ml * 128 + ((ch ^ (ml & 15)) << 3) + (col & 7)] = f2bf(sp(vac[nt][r]));
                }
            }
            #pragma unroll
            for (int kk = 0; kk < 4; ++kk)
                af[kk] = *reinterpret_cast<const short8*>(hl + ml2 * 128 + (((kk * 4 + q) ^ cl) << 3));
            __syncthreads();
            stage_wb(Wb + (size_t)(2 + l) * 16384, wl, t);
            __syncthreads();
        }

        floatx4 acc[8];
        #pragma unroll
        for (int nt = 0; nt < 8; ++nt) acc[nt] = (floatx4){0.f, 0.f, 0.f, 0.f};
        mfma_gemm(wl, af, cl, q, acc);

        const float* b1 = rb1 + (size_t)l * DD;
        #pragma unroll
        for (int nt = 0; nt < 8; ++nt) {
            const int col = nt * 16 + cl;
            const int ch = col >> 3;
            const float bb = b1[col];
            #pragma unroll
            for (int r = 0; r < 4; ++r) {
                const int ml = wv * 16 + q * 4 + r;
                hl[ml * 128 + ((ch ^ (ml & 15)) << 3) + (col & 7)] = f2bf(sp(acc[nt][r] + bb));
            }
        }
        short8 af2[4];
        #pragma unroll
        for (int kk = 0; kk < 4; ++kk)
            af2[kk] = *reinterpret_cast<const short8*>(hl + ml2 * 128 + (((kk * 4 + q) ^ cl) << 3));

        __syncthreads();
        stage_wb(Wb + (size_t)(5 + l) * 16384, wl, t);
        __syncthreads();

        #pragma unroll
        for (int nt = 0; nt < 8; ++nt) acc[nt] = (floatx4){0.f, 0.f, 0.f, 0.f};
        mfma_gemm(wl, af2, cl, q, acc);

        const float* b2 = rb2 + (size_t)l * DD;
        #pragma unroll
        for (int nt = 0; nt < 8; ++nt) {
            const float bb = b2[nt * 16 + cl];
            #pragma unroll
            for (int r = 0; r < 4; ++r) vac[nt][r] += acc[nt][r] + bb;
        }
    }

    __syncthreads();
    stage_wb(Wb + (size_t)8 * 16384, wl, t);
    #pragma unroll
    for (int i = 0; i < 8; ++i) {
        const int c = t + i * 256;
        const int row = c >> 5;
        const int chv = c & 31;
        float4 val = make_float4(0.f, 0.f, 0.f, 0.f);
        if (mb + row < n) val = reinterpret_cast<const float4*>(x)[(size_t)mb * 32 + c];
        *reinterpret_cast<float4*>(vt + row * 128 + ((chv ^ (row & 15)) << 2)) = val;
    }
    __syncthreads();

    #pragma unroll
    for (int nt = 0; nt < 8; ++nt) {
        const int col = nt * 16 + cl;
        const int ch = col >> 3;
        #pragma unroll
        for (int r = 0; r < 4; ++r) {
            const int ml = wv * 16 + q * 4 + r;
            hl[ml * 128 + ((ch ^ (ml & 15)) << 3) + (col & 7)] = f2bf(sp(vac[nt][r]));
        }
    }
    short8 aff[4];
    #pragma unroll
    for (int kk = 0; kk < 4; ++kk)
        aff[kk] = *reinterpret_cast<const short8*>(hl + ml2 * 128 + (((kk * 4 + q) ^ cl) << 3));

    floatx4 acc[8];
    #pragma unroll
    for (int nt = 0; nt < 8; ++nt) acc[nt] = (floatx4){0.f, 0.f, 0.f, 0.f};
    mfma_gemm(wl, aff, cl, q, acc);

    #pragma unroll
    for (int nt = 0; nt < 8; ++nt) {
        const int col = nt * 16 + cl;
        const float bb = bf[col];
        const float uu = u[col];
        const int chv = col >> 2;
        #pragma unroll
        for (int r = 0; r < 4; ++r) {
            const int rl = wv * 16 + q * 4 + r;
            const int row = mb + rl;
            if (row < n) {
                const float xv = vt[rl * 128 + ((chv ^ (rl & 15)) << 2) + (col & 3)];
                out[(size_t)row * DD + col] = acc[nt][r] + bb + uu * xv;
            }
        }
    }
}

// ---------- scan ----------

__global__ __launch_bounds__(256)
void scan_reduce(const int* __restrict__ cnt, int* __restrict__ bsum, int n)
{
    __shared__ int wsum[4];
    const int t = threadIdx.x;
    const int lane = t & 63, wv = t >> 6;
    const int i0 = blockIdx.x * 1024 + t * 4;
    int s = 0;
    #pragma unroll
    for (int k = 0; k < 4; ++k) if (i0 + k < n) s += cnt[i0 + k];
    #pragma unroll
    for (int d = 1; d < 64; d <<= 1) s += __shfl_down(s, d, 64);
    if (lane == 0) wsum[wv] = s;
    __syncthreads();
    if (t == 0) bsum[blockIdx.x] = wsum[0] + wsum[1] + wsum[2] + wsum[3];
}

__global__ __launch_bounds__(256)
void scan_apply(const int* __restrict__ cnt, const int* __restrict__ bsum,
                int* __restrict__ off, int* __restrict__ cnt2, int n, int nb)
{
    __shared__ int wsum[4];
    const int t = threadIdx.x;
    const int lane = t & 63, wv = t >> 6;

    int bval = (lane < nb && lane < (int)blockIdx.x) ? bsum[lane] : 0;
    #pragma unroll
    for (int d = 32; d >= 1; d >>= 1) bval += __shfl_down(bval, d, 64);
    const int blk_off = __shfl(bval, 0, 64);

    const int i0 = blockIdx.x * 1024 + t * 4;
    const int v0 = (i0 + 0 < n) ? cnt[i0 + 0] : 0;
    const int v1 = (i0 + 1 < n) ? cnt[i0 + 1] : 0;
    const int v2 = (i0 + 2 < n) ? cnt[i0 + 2] : 0;
    const int v3 = (i0 + 3 < n) ? cnt[i0 + 3] : 0;
    const int s = v0 + v1 + v2 + v3;
    int incl = s;
    #pragma unroll
    for (int d = 1; d < 64; d <<= 1) {
        const int y = __shfl_up(incl, d, 64);
        if (lane >= d) incl += y;
    }
    if (lane == 63) wsum[wv] = incl;
    __syncthreads();
    int woff = blk_off;
    #pragma unroll
    for (int w = 0; w < 4; ++w) if (w < wv) woff += wsum[w];
    const int excl = woff + incl - s;
    if (i0 + 0 < n) { off[i0 + 0] = excl;                cnt2[i0 + 0] = 0; }
    if (i0 + 1 < n) { off[i0 + 1] = excl + v0;           cnt2[i0 + 1] = 0; }
    if (i0 + 2 < n) { off[i0 + 2] = excl + v0 + v1;      cnt2[i0 + 2] = 0; }
    if (i0 + 3 < n) { off[i0 + 3] = excl + v0 + v1 + v2; cnt2[i0 + 3] = 0; }
}

// grid-stride waves over atoms; R4/R7-proven load structure.
// GH=1: fp16-packed gate math reading preconverted g-half rows.
// GH=0: exact R7 f32 body (fallback).
template<int GH>
__global__ __launch_bounds__(256, 4)
void agg_kernel(const int* __restrict__ off, const int* __restrict__ cnt,
                const int2* __restrict__ spair,
                const unsigned short* __restrict__ gh,
                const float* __restrict__ g,
                const float* __restrict__ Wg, const float* __restrict__ bg,
                const unsigned short* __restrict__ A, float* __restrict__ v, int N)
{
    const int t = threadIdx.x;
    const int lane = t & 63;
    const int wid0 = blockIdx.x * 4 + (t >> 6);
    const int nw   = gridDim.x * 4;
    const int d0 = lane << 1;

    const float bg0 = bg[d0], bg1 = bg[d0 + 1];

    if (GH) {
        __half2 w0h[10], w1h[10];
        #pragma unroll
        for (int k2 = 0; k2 < 10; ++k2) {
            w0h[k2] = __floats2half2_rn(Wg[d0 * 20 + 2 * k2], Wg[d0 * 20 + 2 * k2 + 1]);
            w1h[k2] = __floats2half2_rn(Wg[(d0 + 1) * 20 + 2 * k2], Wg[(d0 + 1) * 20 + 2 * k2 + 1]);
        }

        for (int i = wid0; i < N; i += nw) {
            const int beg = off[i], num = cnt[i], end = beg + num;
            float2 acc = *reinterpret_cast<const float2*>(v + (size_t)i * DD + d0);

            int p = beg;
            while (p + 4 <= end) {
                int ee[4], jj[4];
                #pragma unroll
                for (int u = 0; u < 4; ++u) {
                    const int2 pr = spair[p + u];
                    ee[u] = __builtin_amdgcn_readfirstlane(pr.x);
                    jj[u] = __builtin_amdgcn_readfirstlane(pr.y);
                }
                uint32 aa[4];
                float2 gq[4][5];
                #pragma unroll
                for (int u = 0; u < 4; ++u) {
                    aa[u] = *reinterpret_cast<const uint32*>(A + (size_t)jj[u] * DD + d0);
                    const float2* gp = reinterpret_cast<const float2*>(gh + (size_t)ee[u] * 20);
                    #pragma unroll
                    for (int q2 = 0; q2 < 5; ++q2) gq[u][q2] = gp[q2];
                }
                #pragma unroll
                for (int u = 0; u < 4; ++u) {
                    __half2 a0 = __float2half2_rn(0.f), a1 = __float2half2_rn(0.f);
                    #pragma unroll
                    for (int q2 = 0; q2 < 5; ++q2) {
                        const __half2 h0 = __builtin_bit_cast(__half2, gq[u][q2].x);
                        const __half2 h1 = __builtin_bit_cast(__half2, gq[u][q2].y);
                        a0 = __hfma2(h0, w0h[2 * q2], a0);
                        a1 = __hfma2(h0, w1h[2 * q2], a1);
                        a0 = __hfma2(h1, w0h[2 * q2 + 1], a0);
                        a1 = __hfma2(h1, w1h[2 * q2 + 1], a1);
                    }
                    const float t0 = bg0 + __low2float(a0) + __high2float(a0);
                    const float t1 = bg1 + __low2float(a1) + __high2float(a1);
                    union { uint32 u32; float f; } cx, cy;
                    cx.u32 = aa[u] << 16;
                    cy.u32 = aa[u] & 0xffff0000u;
                    acc.x = fmaf(cx.f, t0, acc.x);
                    acc.y = fmaf(cy.f, t1, acc.y);
                }
                p += 4;
            }
            for (; p < end; ++p) {
                const int2 pr = spair[p];
                const int e0 = __builtin_amdgcn_readfirstlane(pr.x);
                const int j0 = __builtin_amdgcn_readfirstlane(pr.y);
                const uint32 a0u = *reinterpret_cast<const uint32*>(A + (size_t)j0 * DD + d0);
                const float2* gp = reinterpret_cast<const float2*>(gh + (size_t)e0 * 20);
                __half2 a0 = __float2half2_rn(0.f), a1 = __float2half2_rn(0.f);
                #pragma unroll
                for (int q2 = 0; q2 < 5; ++q2) {
                    const float2 qq = gp[q2];
                    const __half2 h0 = __builtin_bit_cast(__half2, qq.x);
                    const __half2 h1 = __builtin_bit_cast(__half2, qq.y);
                    a0 = __hfma2(h0, w0h[2 * q2], a0);
                    a1 = __hfma2(h0, w1h[2 * q2], a1);
                    a0 = __hfma2(h1, w0h[2 * q2 + 1], a0);
                    a1 = __hfma2(h1, w1h[2 * q2 + 1], a1);
                }
                const float t0 = bg0 + __low2float(a0) + __high2float(a0);
                const float t1 = bg1 + __low2float(a1) + __high2float(a1);
                union { uint32 u32; float f; } cx, cy;
                cx.u32 = a0u << 16;
                cy.u32 = a0u & 0xffff0000u;
                acc.x = fmaf(cx.f, t0, acc.x);
                acc.y = fmaf(cy.f, t1, acc.y);
            }
            *reinterpret_cast<float2*>(v + (size_t)i * DD + d0) = acc;
        }
    } else {
        float2 wg01[20];
        #pragma unroll
        for (int k = 0; k < 20; ++k) {
            wg01[k].x = Wg[d0 * 20 + k];
            wg01[k].y = Wg[(d0 + 1) * 20 + k];
        }
        for (int i = wid0; i < N; i += nw) {
            const int beg = off[i], num = cnt[i], end = beg + num;
            float2 acc = *reinterpret_cast<const float2*>(v + (size_t)i * DD + d0);
            int p = beg;
            for (; p + 2 <= end; p += 2) {
                const int2 pr0 = spair[p];
                const int2 pr1 = spair[p + 1];
                const int e0 = __builtin_amdgcn_readfirstlane(pr0.x);
                const int j0 = __builtin_amdgcn_readfirstlane(pr0.y);
                const int e1 = __builtin_amdgcn_readfirstlane(pr1.x);
                const int j1 = __builtin_amdgcn_readfirstlane(pr1.y);
                const uint32 a0 = *reinterpret_cast<const uint32*>(A + (size_t)j0 * DD + d0);
                const uint32 a1 = *reinterpret_cast<const uint32*>(A + (size_t)j1 * DD + d0);
                const float4* g0p = reinterpret_cast<const float4*>(g + (size_t)e0 * 20);
                const float4* g1p = reinterpret_cast<const float4*>(g + (size_t)e1 * 20);
                float2 t0 = make_float2(bg0, bg1), t1 = make_float2(bg0, bg1);
                #pragma unroll
                for (int qq = 0; qq < 5; ++qq) {
                    const float4 p0 = g0p[qq];
                    const float4 p1 = g1p[qq];
                    t0.x = fmaf(p0.x, wg01[qq*4+0].x, t0.x); t0.y = fmaf(p0.x, wg01[qq*4+0].y, t0.y);
                    t0.x = fmaf(p0.y, wg01[qq*4+1].x, t0.x); t0.y = fmaf(p0.y, wg01[qq*4+1].y, t0.y);
                    t0.x = fmaf(p0.z, wg01[qq*4+2].x, t0.x); t0.y = fmaf(p0.z, wg01[qq*4+2].y, t0.y);
                    t0.x = fmaf(p0.w, wg01[qq*4+3].x, t0.x); t0.y = fmaf(p0.w, wg01[qq*4+3].y, t0.y);
                    t1.x = fmaf(p1.x, wg01[qq*4+0].x, t1.x); t1.y = fmaf(p1.x, wg01[qq*4+0].y, t1.y);
                    t1.x = fmaf(p1.y, wg01[qq*4+1].x, t1.x); t1.y = fmaf(p1.y, wg01[qq*4+1].y, t1.y);
                    t1.x = fmaf(p1.z, wg01[qq*4+2].x, t1.x); t1.y = fmaf(p1.z, wg01[qq*4+2].y, t1.y);
                    t1.x = fmaf(p1.w, wg01[qq*4+3].x, t1.x); t1.y = fmaf(p1.w, wg01[qq*4+3].y, t1.y);
                }
                union { uint32 u; float f; } c0x, c0y, c1x, c1y;
                c0x.u = a0 << 16; c0y.u = a0 & 0xffff0000u;
                c1x.u = a1 << 16; c1y.u = a1 & 0xffff0000u;
                acc.x = fmaf(c0x.f, t0.x, acc.x); acc.y = fmaf(c0y.f, t0.y, acc.y);
                acc.x = fmaf(c1x.f, t1.x, acc.x); acc.y = fmaf(c1y.f, t1.y, acc.y);
            }
            if (p < end) {
                const int2 pr0 = spair[p];
                const int e0 = __builtin_amdgcn_readfirstlane(pr0.x);
                const int j0 = __builtin_amdgcn_readfirstlane(pr0.y);
                const uint32 a0 = *reinterpret_cast<const uint32*>(A + (size_t)j0 * DD + d0);
                const float4* g0p = reinterpret_cast<const float4*>(g + (size_t)e0 * 20);
                float2 t0 = make_float2(bg0, bg1);
                #pragma unroll
                for (int qq = 0; qq < 5; ++qq) {
                    const float4 p0 = g0p[qq];
                    t0.x = fmaf(p0.x, wg01[qq*4+0].x, t0.x); t0.y = fmaf(p0.x, wg01[qq*4+0].y, t0.y);
                    t0.x = fmaf(p0.y, wg01[qq*4+1].x, t0.x); t0.y = fmaf(p0.y, wg01[qq*4+1].y, t0.y);
                    t0.x = fmaf(p0.z, wg01[qq*4+2].x, t0.x); t0.y = fmaf(p0.z, wg01[qq*4+2].y, t0.y);
                    t0.x = fmaf(p0.w, wg01[qq*4+3].x, t0.x); t0.y = fmaf(p0.w, wg01[qq*4+3].y, t0.y);
                }
                union { uint32 u; float f; } c0x, c0y;
                c0x.u = a0 << 16; c0y.u = a0 & 0xffff0000u;
                acc.x = fmaf(c0x.f, t0.x, acc.x); acc.y = fmaf(c0y.f, t0.y, acc.y);
            }
            *reinterpret_cast<float2*>(v + (size_t)i * DD + d0) = acc;
        }
    }
}

extern "C" void kernel_launch(void* const* d_in, const int* in_sizes, int n_in,
                              void* d_out, int out_size, void* d_ws, size_t ws_size,
                              hipStream_t stream)
{
    const float* x     = (const float*)d_in[0];
    const float* g     = (const float*)d_in[1];
    const int*   idx_i = (const int*)d_in[2];
    const int*   idx_j = (const int*)d_in[3];
    const float* u     = (const float*)d_in[5];
    const float* Wf    = (const float*)d_in[6];
    const float* bf    = (const float*)d_in[7];
    const float* Wg    = (const float*)d_in[8];
    const float* bg    = (const float*)d_in[9];
    const float* Wj    = (const float*)d_in[10];
    const float* bj    = (const float*)d_in[11];
    const float* Wi    = (const float*)d_in[12];
    const float* bi    = (const float*)d_in[13];
    const float* rw1   = (const float*)d_in[14];
    const float* rb1   = (const float*)d_in[15];
    const float* rw2   = (const float*)d_in[16];
    const float* rb2   = (const float*)d_in[17];

    const int N = in_sizes[0] / DD;   // 50000
    const int E = in_sizes[2];        // 640000
    float* out = (float*)d_out;

    // workspace layout
    float*          v     = (float*)d_ws;                           // [N,128] f32
    unsigned short* A     = (unsigned short*)(v + (size_t)N * DD);  // [N,128] bf16
    int*            cnt   = (int*)(A + (size_t)N * DD);
    int*            off   = cnt + N;
    int*            cnt2  = off + N;
    int*            bsum  = cnt2 + N;                               // [64]
    int2*           spair = (int2*)(bsum + 64);                     // [E]
    unsigned short* Wb    = (unsigned short*)(spair + E);           // 9*16384 bf16
    unsigned short* gh    = Wb + 9 * 16384;                         // [E*20] fp16

    const size_t need_gh = (size_t)((char*)(gh + (size_t)E * 20) - (char*)d_ws);
    const bool gh_ok = ws_size >= need_gh;

    dim3 blk(256);
    const int tiles    = (N + 63) / 64;
    const int eblocks  = (E + 255) / 256;
    const int sblocks  = (N + 1023) / 1024;   // 49 for N=50000 (<=64 required)
    const int gchunks  = gh_ok ? (E * 20) / 8 : 0;
    const int gblocks  = gh_ok ? (gchunks + 255) / 256 : 0;

    // cnt must be zero before prep (hist folded in)
    hipMemsetAsync(cnt, 0, (size_t)N * sizeof(int), stream);

    prep_kernel<<<72 + gblocks + eblocks, blk, 0, stream>>>(
        Wj, Wi, rw1, rw2, Wf, Wb, g, gh, gchunks, gblocks, idx_i, cnt, E);

    scan_reduce<<<sblocks, blk, 0, stream>>>(cnt, bsum, N);
    scan_apply<<<sblocks, blk, 0, stream>>>(cnt, bsum, off, cnt2, N, sblocks);

    scatter_dual<<<eblocks + tiles, blk, 0, stream>>>(
        idx_i, idx_j, off, cnt2, spair, E, eblocks,
        x, Wb, bj, bi, A, v, N);

    if (gh_ok)
        agg_kernel<1><<<2048, blk, 0, stream>>>(off, cnt, spair, gh, g,
                                                Wg, bg, A, v, N);
    else
        agg_kernel<0><<<2048, blk, 0, stream>>>(off, cnt, spair, gh, g,
                                                Wg, bg, A, v, N);

    tail_kernel<<<tiles, blk, 0, stream>>>(v, x, Wb, rb1, rb2, bf, u, out, N);
}

// Round 15
// 219.148 us; speedup vs baseline: 1.1770x; 1.1033x over previous
//
#include <hip/hip_runtime.h>
#include <hip/hip_fp16.h>

#define DD 128

typedef __attribute__((ext_vector_type(8))) short short8;
typedef __attribute__((ext_vector_type(8))) unsigned short ushort8;
typedef __attribute__((ext_vector_type(4))) float floatx4;
typedef unsigned int uint32;

__device__ __forceinline__ float sp(float x) {
    return fmaxf(x, 0.0f) + __logf(1.0f + __expf(-fabsf(x)));
}

__device__ __forceinline__ unsigned short f2bf(float f) {
    union { float f; uint32 u; } c; c.f = f;
    const uint32 u = c.u;
    return (unsigned short)((u + 0x7fffu + ((u >> 16) & 1u)) >> 16);
}

__device__ __forceinline__ unsigned short f2h(float f) {
    __half h = __float2half(f);
    return __builtin_bit_cast(unsigned short, h);
}

// ---------- fused prep: weights f32->bf16 (swizzled), g f32->fp16, and the
// idx_i histogram WITH rank capture (rank[e] = arrival order within atom) ----------
__global__ __launch_bounds__(256)
void prep_kernel(const float* __restrict__ Wj, const float* __restrict__ Wi,
                 const float* __restrict__ rw1, const float* __restrict__ rw2,
                 const float* __restrict__ Wf, unsigned short* __restrict__ out,
                 const float* __restrict__ g, unsigned short* __restrict__ gh,
                 int gchunks, int gh_blocks,
                 const int* __restrict__ idx_i, int* __restrict__ cnt,
                 int* __restrict__ rank, int E)
{
    const int b = (int)blockIdx.x;
    if (b >= 72 + gh_blocks) {
        // histogram + rank capture (rank write is sequential/coalesced)
        const int e = (b - 72 - gh_blocks) * 256 + threadIdx.x;
        if (e < E) rank[e] = atomicAdd(&cnt[idx_i[e]], 1);
        return;
    }
    if (b >= 72) {
        const int gid = (b - 72) * 256 + threadIdx.x;  // 8-float chunk
        if (gid < gchunks) {
            const float4 f0 = reinterpret_cast<const float4*>(g)[2 * gid];
            const float4 f1 = reinterpret_cast<const float4*>(g)[2 * gid + 1];
            ushort8 o;
            o[0] = f2h(f0.x); o[1] = f2h(f0.y); o[2] = f2h(f0.z); o[3] = f2h(f0.w);
            o[4] = f2h(f1.x); o[5] = f2h(f1.y); o[6] = f2h(f1.z); o[7] = f2h(f1.w);
            reinterpret_cast<ushort8*>(gh)[gid] = o;
        }
        return;
    }
    const int gid = b * 256 + threadIdx.x;   // 8-float chunk id
    const int mat = gid >> 11;
    const int f8  = gid & 2047;
    const float* src;
    if      (mat == 0) src = Wj;
    else if (mat == 1) src = Wi;
    else if (mat <= 4) src = rw1 + (size_t)(mat - 2) * 16384;
    else if (mat <= 7) src = rw2 + (size_t)(mat - 5) * 16384;
    else               src = Wf;
    const int row = f8 >> 4;
    const int ch  = f8 & 15;
    const float4 a = reinterpret_cast<const float4*>(src)[2 * f8];
    const float4 bb = reinterpret_cast<const float4*>(src)[2 * f8 + 1];
    ushort8 u8;
    u8[0] = f2bf(a.x); u8[1] = f2bf(a.y); u8[2] = f2bf(a.z); u8[3] = f2bf(a.w);
    u8[4] = f2bf(bb.x); u8[5] = f2bf(bb.y); u8[6] = f2bf(bb.z); u8[7] = f2bf(bb.w);
    *reinterpret_cast<ushort8*>(out + (size_t)mat * 16384 + row * 128 +
                                ((ch ^ (row & 15)) << 3)) = u8;
}

__device__ __forceinline__ void stage_wb(const unsigned short* __restrict__ Wb,
                                         unsigned short* wl, int t)
{
    #pragma unroll
    for (int i = 0; i < 8; ++i) {
        const int c = t + i * 256;
        *reinterpret_cast<ushort8*>(wl + c * 8) =
            *reinterpret_cast<const ushort8*>(Wb + c * 8);
    }
}

__device__ __forceinline__ void load_afrag_act(const float* __restrict__ X,
                                               int m, int q, int n, short8 af[4])
{
    const int mm = m < n ? m : n - 1;
    const float* row = X + (size_t)mm * DD + q * 8;
    #pragma unroll
    for (int kk = 0; kk < 4; ++kk) {
        const float4 a = *reinterpret_cast<const float4*>(row + kk * 32);
        const float4 b = *reinterpret_cast<const float4*>(row + kk * 32 + 4);
        ushort8 u;
        u[0] = f2bf(sp(a.x)); u[1] = f2bf(sp(a.y)); u[2] = f2bf(sp(a.z)); u[3] = f2bf(sp(a.w));
        u[4] = f2bf(sp(b.x)); u[5] = f2bf(sp(b.y)); u[6] = f2bf(sp(b.z)); u[7] = f2bf(sp(b.w));
        af[kk] = __builtin_bit_cast(short8, u);
    }
}

__device__ __forceinline__ void mfma_gemm(const unsigned short* wl,
                                          const short8 af[4],
                                          int cl, int q, floatx4 acc[8])
{
    #pragma unroll
    for (int nt = 0; nt < 8; ++nt) {
        const int nrow = nt * 16 + cl;
        #pragma unroll
        for (int kk = 0; kk < 4; ++kk) {
            const int chs = (kk * 4 + q) ^ cl;
            const short8 bfr = *reinterpret_cast<const short8*>(wl + nrow * 128 + (chs << 3));
            acc[nt] = __builtin_amdgcn_mfma_f32_16x16x32_bf16(af[kk], bfr, acc[nt], 0, 0, 0);
        }
    }
}

// fused scatter + dual_gemm; scatter is ATOMIC-FREE via precomputed rank
__global__ __launch_bounds__(256, 4)
void scatter_dual(const int* __restrict__ idx_i, const int* __restrict__ idx_j,
                  const int* __restrict__ off, const int* __restrict__ rank,
                  int2* __restrict__ spair, int E, int eblocks,
                  const float* __restrict__ x,
                  const unsigned short* __restrict__ Wb,
                  const float* __restrict__ bj, const float* __restrict__ bi,
                  unsigned short* __restrict__ Aout, float* __restrict__ vout, int n)
{
    __shared__ __align__(16) unsigned short wl[128 * 128];
    const int t = threadIdx.x;

    if ((int)blockIdx.x < eblocks) {
        // ---- scatter (no atomics; pure pipelined stores) ----
        const int e = blockIdx.x * 256 + t;
        if (e < E) {
            const int i = idx_i[e];
            const int p = off[i] + rank[e];
            spair[p] = make_int2(e, idx_j[e]);
        }
        return;
    }

    // ---- dual_gemm ----
    const int bid = (int)blockIdx.x - eblocks;
    const int lane = t & 63, wv = t >> 6;
    const int cl = lane & 15, q = lane >> 4;
    const int m0 = bid * 64 + wv * 16;

    short8 af[4];
    load_afrag_act(x, m0 + cl, q, n, af);

    stage_wb(Wb, wl, t);
    __syncthreads();

    floatx4 acc[8];
    #pragma unroll
    for (int nt = 0; nt < 8; ++nt) acc[nt] = (floatx4){0.f, 0.f, 0.f, 0.f};
    mfma_gemm(wl, af, cl, q, acc);

    #pragma unroll
    for (int nt = 0; nt < 8; ++nt) {
        const int col = nt * 16 + cl;
        const float bb = bj[col];
        #pragma unroll
        for (int r = 0; r < 4; ++r) {
            const int row = m0 + q * 4 + r;
            if (row < n) Aout[(size_t)row * DD + col] = f2bf(sp(acc[nt][r] + bb));
        }
    }

    __syncthreads();
    stage_wb(Wb + 16384, wl, t);
    __syncthreads();

    #pragma unroll
    for (int nt = 0; nt < 8; ++nt) acc[nt] = (floatx4){0.f, 0.f, 0.f, 0.f};
    mfma_gemm(wl, af, cl, q, acc);

    #pragma unroll
    for (int nt = 0; nt < 8; ++nt) {
        const int col = nt * 16 + cl;
        const float bb = bi[col];
        #pragma unroll
        for (int r = 0; r < 4; ++r) {
            const int row = m0 + q * 4 + r;
            if (row < n) vout[(size_t)row * DD + col] = sp(acc[nt][r] + bb);
        }
    }
}

// fused tail (best-known 74us variant): 3 residual layers + final output,
// v kept in registers; vt+hl+wl = 80KB LDS, serial 2-barrier staging.
__global__ __launch_bounds__(256, 2)
void tail_kernel(const float* __restrict__ vin, const float* __restrict__ x,
                 const unsigned short* __restrict__ Wb,
                 const float* __restrict__ rb1, const float* __restrict__ rb2,
                 const float* __restrict__ bf, const float* __restrict__ u,
                 float* __restrict__ out, int n)
{
    __shared__ __align__(16) unsigned short wl[128 * 128];
    __shared__ __align__(16) unsigned short hl[64 * 128];
    __shared__ __align__(16) float vt[64 * 128];
    const int t = threadIdx.x;
    const int lane = t & 63, wv = t >> 6;
    const int cl = lane & 15, q = lane >> 4;
    const int mb = blockIdx.x * 64;

    #pragma unroll
    for (int i = 0; i < 8; ++i) {
        const int c = t + i * 256;
        const int row = c >> 5;
        const int chv = c & 31;
        float4 val = make_float4(0.f, 0.f, 0.f, 0.f);
        if (mb + row < n) val = reinterpret_cast<const float4*>(vin)[(size_t)mb * 32 + c];
        *reinterpret_cast<float4*>(vt + row * 128 + ((chv ^ (row & 15)) << 2)) = val;
    }
    stage_wb(Wb + 2 * 16384, wl, t);
    __syncthreads();

    floatx4 vac[8];
    #pragma unroll
    for (int nt = 0; nt < 8; ++nt) {
        #pragma unroll
        for (int r = 0; r < 4; ++r) {
            const int rl = wv * 16 + q * 4 + r;
            const int col = nt * 16 + cl;
            const int chv = col >> 2;
            vac[nt][r] = vt[rl * 128 + ((chv ^ (rl & 15)) << 2) + (col & 3)];
        }
    }

    short8 af[4];
    {
        const int rl = wv * 16 + cl;
        #pragma unroll
        for (int kk = 0; kk < 4; ++kk) {
            const int c0 = q * 2 + kk * 8;
            const floatx4 A0 = *reinterpret_cast<const floatx4*>(vt + rl * 128 + (((c0    ) ^ cl) << 2));
            const floatx4 A1 = *reinterpret_cast<const floatx4*>(vt + rl * 128 + (((c0 + 1) ^ cl) << 2));
            ushort8 u8;
            u8[0] = f2bf(sp(A0[0])); u8[1] = f2bf(sp(A0[1])); u8[2] = f2bf(sp(A0[2])); u8[3] = f2bf(sp(A0[3]));
            u8[4] = f2bf(sp(A1[0])); u8[5] = f2bf(sp(A1[1])); u8[6] = f2bf(sp(A1[2])); u8[7] = f2bf(sp(A1[3]));
            af[kk] = __builtin_bit_cast(short8, u8);
        }
    }

    const int ml2 = wv * 16 + cl;

    for (int l = 0; l < 3; ++l) {
        if (l > 0) {
            #pragma unroll
            for (int nt = 0; nt < 8; ++nt) {
                const int col = nt * 16 + cl;
                const int ch = col >> 3;
                #pragma unroll
                for (int r = 0; r < 4; ++r) {
                    const int ml = wv * 16 + q * 4 + r;
                    hl[ml * 128 + ((ch ^ (ml & 15)) << 3) + (col & 7)] = f2bf(sp(vac[nt][r]));
                }
            }
            #pragma unroll
            for (int kk = 0; kk < 4; ++kk)
                af[kk] = *reinterpret_cast<const short8*>(hl + ml2 * 128 + (((kk * 4 + q) ^ cl) << 3));
            __syncthreads();
            stage_wb(Wb + (size_t)(2 + l) * 16384, wl, t);
            __syncthreads();
        }

        floatx4 acc[8];
        #pragma unroll
        for (int nt = 0; nt < 8; ++nt) acc[nt] = (floatx4){0.f, 0.f, 0.f, 0.f};
        mfma_gemm(wl, af, cl, q, acc);

        const float* b1 = rb1 + (size_t)l * DD;
        #pragma unroll
        for (int nt = 0; nt < 8; ++nt) {
            const int col = nt * 16 + cl;
            const int ch = col >> 3;
            const float bb = b1[col];
            #pragma unroll
            for (int r = 0; r < 4; ++r) {
                const int ml = wv * 16 + q * 4 + r;
                hl[ml * 128 + ((ch ^ (ml & 15)) << 3) + (col & 7)] = f2bf(sp(acc[nt][r] + bb));
            }
        }
        short8 af2[4];
        #pragma unroll
        for (int kk = 0; kk < 4; ++kk)
            af2[kk] = *reinterpret_cast<const short8*>(hl + ml2 * 128 + (((kk * 4 + q) ^ cl) << 3));

        __syncthreads();
        stage_wb(Wb + (size_t)(5 + l) * 16384, wl, t);
        __syncthreads();

        #pragma unroll
        for (int nt = 0; nt < 8; ++nt) acc[nt] = (floatx4){0.f, 0.f, 0.f, 0.f};
        mfma_gemm(wl, af2, cl, q, acc);

        const float* b2 = rb2 + (size_t)l * DD;
        #pragma unroll
        for (int nt = 0; nt < 8; ++nt) {
            const float bb = b2[nt * 16 + cl];
            #pragma unroll
            for (int r = 0; r < 4; ++r) vac[nt][r] += acc[nt][r] + bb;
        }
    }

    __syncthreads();
    stage_wb(Wb + (size_t)8 * 16384, wl, t);
    #pragma unroll
    for (int i = 0; i < 8; ++i) {
        const int c = t + i * 256;
        const int row = c >> 5;
        const int chv = c & 31;
        float4 val = make_float4(0.f, 0.f, 0.f, 0.f);
        if (mb + row < n) val = reinterpret_cast<const float4*>(x)[(size_t)mb * 32 + c];
        *reinterpret_cast<float4*>(vt + row * 128 + ((chv ^ (row & 15)) << 2)) = val;
    }
    __syncthreads();

    #pragma unroll
    for (int nt = 0; nt < 8; ++nt) {
        const int col = nt * 16 + cl;
        const int ch = col >> 3;
        #pragma unroll
        for (int r = 0; r < 4; ++r) {
            const int ml = wv * 16 + q * 4 + r;
            hl[ml * 128 + ((ch ^ (ml & 15)) << 3) + (col & 7)] = f2bf(sp(vac[nt][r]));
        }
    }
    short8 aff[4];
    #pragma unroll
    for (int kk = 0; kk < 4; ++kk)
        aff[kk] = *reinterpret_cast<const short8*>(hl + ml2 * 128 + (((kk * 4 + q) ^ cl) << 3));

    floatx4 acc[8];
    #pragma unroll
    for (int nt = 0; nt < 8; ++nt) acc[nt] = (floatx4){0.f, 0.f, 0.f, 0.f};
    mfma_gemm(wl, aff, cl, q, acc);

    #pragma unroll
    for (int nt = 0; nt < 8; ++nt) {
        const int col = nt * 16 + cl;
        const float bb = bf[col];
        const float uu = u[col];
        const int chv = col >> 2;
        #pragma unroll
        for (int r = 0; r < 4; ++r) {
            const int rl = wv * 16 + q * 4 + r;
            const int row = mb + rl;
            if (row < n) {
                const float xv = vt[rl * 128 + ((chv ^ (rl & 15)) << 2) + (col & 3)];
                out[(size_t)row * DD + col] = acc[nt][r] + bb + uu * xv;
            }
        }
    }
}

// ---------- scan ----------

__global__ __launch_bounds__(256)
void scan_reduce(const int* __restrict__ cnt, int* __restrict__ bsum, int n)
{
    __shared__ int wsum[4];
    const int t = threadIdx.x;
    const int lane = t & 63, wv = t >> 6;
    const int i0 = blockIdx.x * 1024 + t * 4;
    int s = 0;
    #pragma unroll
    for (int k = 0; k < 4; ++k) if (i0 + k < n) s += cnt[i0 + k];
    #pragma unroll
    for (int d = 1; d < 64; d <<= 1) s += __shfl_down(s, d, 64);
    if (lane == 0) wsum[wv] = s;
    __syncthreads();
    if (t == 0) bsum[blockIdx.x] = wsum[0] + wsum[1] + wsum[2] + wsum[3];
}

__global__ __launch_bounds__(256)
void scan_apply(const int* __restrict__ cnt, const int* __restrict__ bsum,
                int* __restrict__ off, int n, int nb)
{
    __shared__ int wsum[4];
    const int t = threadIdx.x;
    const int lane = t & 63, wv = t >> 6;

    int bval = (lane < nb && lane < (int)blockIdx.x) ? bsum[lane] : 0;
    #pragma unroll
    for (int d = 32; d >= 1; d >>= 1) bval += __shfl_down(bval, d, 64);
    const int blk_off = __shfl(bval, 0, 64);

    const int i0 = blockIdx.x * 1024 + t * 4;
    const int v0 = (i0 + 0 < n) ? cnt[i0 + 0] : 0;
    const int v1 = (i0 + 1 < n) ? cnt[i0 + 1] : 0;
    const int v2 = (i0 + 2 < n) ? cnt[i0 + 2] : 0;
    const int v3 = (i0 + 3 < n) ? cnt[i0 + 3] : 0;
    const int s = v0 + v1 + v2 + v3;
    int incl = s;
    #pragma unroll
    for (int d = 1; d < 64; d <<= 1) {
        const int y = __shfl_up(incl, d, 64);
        if (lane >= d) incl += y;
    }
    if (lane == 63) wsum[wv] = incl;
    __syncthreads();
    int woff = blk_off;
    #pragma unroll
    for (int w = 0; w < 4; ++w) if (w < wv) woff += wsum[w];
    const int excl = woff + incl - s;
    if (i0 + 0 < n) off[i0 + 0] = excl;
    if (i0 + 1 < n) off[i0 + 1] = excl + v0;
    if (i0 + 2 < n) off[i0 + 2] = excl + v0 + v1;
    if (i0 + 3 < n) off[i0 + 3] = excl + v0 + v1 + v2;
}

// grid-stride waves over atoms; R4/R7-proven load structure.
// GH=1: fp16-packed gate math reading preconverted g-half rows.
// GH=0: exact R7 f32 body (fallback).
template<int GH>
__global__ __launch_bounds__(256, 4)
void agg_kernel(const int* __restrict__ off, const int* __restrict__ cnt,
                const int2* __restrict__ spair,
                const unsigned short* __restrict__ gh,
                const float* __restrict__ g,
                const float* __restrict__ Wg, const float* __restrict__ bg,
                const unsigned short* __restrict__ A, float* __restrict__ v, int N)
{
    const int t = threadIdx.x;
    const int lane = t & 63;
    const int wid0 = blockIdx.x * 4 + (t >> 6);
    const int nw   = gridDim.x * 4;
    const int d0 = lane << 1;

    const float bg0 = bg[d0], bg1 = bg[d0 + 1];

    if (GH) {
        __half2 w0h[10], w1h[10];
        #pragma unroll
        for (int k2 = 0; k2 < 10; ++k2) {
            w0h[k2] = __floats2half2_rn(Wg[d0 * 20 + 2 * k2], Wg[d0 * 20 + 2 * k2 + 1]);
            w1h[k2] = __floats2half2_rn(Wg[(d0 + 1) * 20 + 2 * k2], Wg[(d0 + 1) * 20 + 2 * k2 + 1]);
        }

        for (int i = wid0; i < N; i += nw) {
            const int beg = off[i], num = cnt[i], end = beg + num;
            float2 acc = *reinterpret_cast<const float2*>(v + (size_t)i * DD + d0);

            int p = beg;
            while (p + 4 <= end) {
                int ee[4], jj[4];
                #pragma unroll
                for (int u = 0; u < 4; ++u) {
                    const int2 pr = spair[p + u];
                    ee[u] = __builtin_amdgcn_readfirstlane(pr.x);
                    jj[u] = __builtin_amdgcn_readfirstlane(pr.y);
                }
                uint32 aa[4];
                float2 gq[4][5];
                #pragma unroll
                for (int u = 0; u < 4; ++u) {
                    aa[u] = *reinterpret_cast<const uint32*>(A + (size_t)jj[u] * DD + d0);
                    const float2* gp = reinterpret_cast<const float2*>(gh + (size_t)ee[u] * 20);
                    #pragma unroll
                    for (int q2 = 0; q2 < 5; ++q2) gq[u][q2] = gp[q2];
                }
                #pragma unroll
                for (int u = 0; u < 4; ++u) {
                    __half2 a0 = __float2half2_rn(0.f), a1 = __float2half2_rn(0.f);
                    #pragma unroll
                    for (int q2 = 0; q2 < 5; ++q2) {
                        const __half2 h0 = __builtin_bit_cast(__half2, gq[u][q2].x);
                        const __half2 h1 = __builtin_bit_cast(__half2, gq[u][q2].y);
                        a0 = __hfma2(h0, w0h[2 * q2], a0);
                        a1 = __hfma2(h0, w1h[2 * q2], a1);
                        a0 = __hfma2(h1, w0h[2 * q2 + 1], a0);
                        a1 = __hfma2(h1, w1h[2 * q2 + 1], a1);
                    }
                    const float t0 = bg0 + __low2float(a0) + __high2float(a0);
                    const float t1 = bg1 + __low2float(a1) + __high2float(a1);
                    union { uint32 u32; float f; } cx, cy;
                    cx.u32 = aa[u] << 16;
                    cy.u32 = aa[u] & 0xffff0000u;
                    acc.x = fmaf(cx.f, t0, acc.x);
                    acc.y = fmaf(cy.f, t1, acc.y);
                }
                p += 4;
            }
            for (; p < end; ++p) {
                const int2 pr = spair[p];
                const int e0 = __builtin_amdgcn_readfirstlane(pr.x);
                const int j0 = __builtin_amdgcn_readfirstlane(pr.y);
                const uint32 a0u = *reinterpret_cast<const uint32*>(A + (size_t)j0 * DD + d0);
                const float2* gp = reinterpret_cast<const float2*>(gh + (size_t)e0 * 20);
                __half2 a0 = __float2half2_rn(0.f), a1 = __float2half2_rn(0.f);
                #pragma unroll
                for (int q2 = 0; q2 < 5; ++q2) {
                    const float2 qq = gp[q2];
                    const __half2 h0 = __builtin_bit_cast(__half2, qq.x);
                    const __half2 h1 = __builtin_bit_cast(__half2, qq.y);
                    a0 = __hfma2(h0, w0h[2 * q2], a0);
                    a1 = __hfma2(h0, w1h[2 * q2], a1);
                    a0 = __hfma2(h1, w0h[2 * q2 + 1], a0);
                    a1 = __hfma2(h1, w1h[2 * q2 + 1], a1);
                }
                const float t0 = bg0 + __low2float(a0) + __high2float(a0);
                const float t1 = bg1 + __low2float(a1) + __high2float(a1);
                union { uint32 u32; float f; } cx, cy;
                cx.u32 = a0u << 16;
                cy.u32 = a0u & 0xffff0000u;
                acc.x = fmaf(cx.f, t0, acc.x);
                acc.y = fmaf(cy.f, t1, acc.y);
            }
            *reinterpret_cast<float2*>(v + (size_t)i * DD + d0) = acc;
        }
    } else {
        float2 wg01[20];
        #pragma unroll
        for (int k = 0; k < 20; ++k) {
            wg01[k].x = Wg[d0 * 20 + k];
            wg01[k].y = Wg[(d0 + 1) * 20 + k];
        }
        for (int i = wid0; i < N; i += nw) {
            const int beg = off[i], num = cnt[i], end = beg + num;
            float2 acc = *reinterpret_cast<const float2*>(v + (size_t)i * DD + d0);
            int p = beg;
            for (; p + 2 <= end; p += 2) {
                const int2 pr0 = spair[p];
                const int2 pr1 = spair[p + 1];
                const int e0 = __builtin_amdgcn_readfirstlane(pr0.x);
                const int j0 = __builtin_amdgcn_readfirstlane(pr0.y);
                const int e1 = __builtin_amdgcn_readfirstlane(pr1.x);
                const int j1 = __builtin_amdgcn_readfirstlane(pr1.y);
                const uint32 a0 = *reinterpret_cast<const uint32*>(A + (size_t)j0 * DD + d0);
                const uint32 a1 = *reinterpret_cast<const uint32*>(A + (size_t)j1 * DD + d0);
                const float4* g0p = reinterpret_cast<const float4*>(g + (size_t)e0 * 20);
                const float4* g1p = reinterpret_cast<const float4*>(g + (size_t)e1 * 20);
                float2 t0 = make_float2(bg0, bg1), t1 = make_float2(bg0, bg1);
                #pragma unroll
                for (int qq = 0; qq < 5; ++qq) {
                    const float4 p0 = g0p[qq];
                    const float4 p1 = g1p[qq];
                    t0.x = fmaf(p0.x, wg01[qq*4+0].x, t0.x); t0.y = fmaf(p0.x, wg01[qq*4+0].y, t0.y);
                    t0.x = fmaf(p0.y, wg01[qq*4+1].x, t0.x); t0.y = fmaf(p0.y, wg01[qq*4+1].y, t0.y);
                    t0.x = fmaf(p0.z, wg01[qq*4+2].x, t0.x); t0.y = fmaf(p0.z, wg01[qq*4+2].y, t0.y);
                    t0.x = fmaf(p0.w, wg01[qq*4+3].x, t0.x); t0.y = fmaf(p0.w, wg01[qq*4+3].y, t0.y);
                    t1.x = fmaf(p1.x, wg01[qq*4+0].x, t1.x); t1.y = fmaf(p1.x, wg01[qq*4+0].y, t1.y);
                    t1.x = fmaf(p1.y, wg01[qq*4+1].x, t1.x); t1.y = fmaf(p1.y, wg01[qq*4+1].y, t1.y);
                    t1.x = fmaf(p1.z, wg01[qq*4+2].x, t1.x); t1.y = fmaf(p1.z, wg01[qq*4+2].y, t1.y);
                    t1.x = fmaf(p1.w, wg01[qq*4+3].x, t1.x); t1.y = fmaf(p1.w, wg01[qq*4+3].y, t1.y);
                }
                union { uint32 u; float f; } c0x, c0y, c1x, c1y;
                c0x.u = a0 << 16; c0y.u = a0 & 0xffff0000u;
                c1x.u = a1 << 16; c1y.u = a1 & 0xffff0000u;
                acc.x = fmaf(c0x.f, t0.x, acc.x); acc.y = fmaf(c0y.f, t0.y, acc.y);
                acc.x = fmaf(c1x.f, t1.x, acc.x); acc.y = fmaf(c1y.f, t1.y, acc.y);
            }
            if (p < end) {
                const int2 pr0 = spair[p];
                const int e0 = __builtin_amdgcn_readfirstlane(pr0.x);
                const int j0 = __builtin_amdgcn_readfirstlane(pr0.y);
                const uint32 a0 = *reinterpret_cast<const uint32*>(A + (size_t)j0 * DD + d0);
                const float4* g0p = reinterpret_cast<const float4*>(g + (size_t)e0 * 20);
                float2 t0 = make_float2(bg0, bg1);
                #pragma unroll
                for (int qq = 0; qq < 5; ++qq) {
                    const float4 p0 = g0p[qq];
                    t0.x = fmaf(p0.x, wg01[qq*4+0].x, t0.x); t0.y = fmaf(p0.x, wg01[qq*4+0].y, t0.y);
                    t0.x = fmaf(p0.y, wg01[qq*4+1].x, t0.x); t0.y = fmaf(p0.y, wg01[qq*4+1].y, t0.y);
                    t0.x = fmaf(p0.z, wg01[qq*4+2].x, t0.x); t0.y = fmaf(p0.z, wg01[qq*4+2].y, t0.y);
                    t0.x = fmaf(p0.w, wg01[qq*4+3].x, t0.x); t0.y = fmaf(p0.w, wg01[qq*4+3].y, t0.y);
                }
                union { uint32 u; float f; } c0x, c0y;
                c0x.u = a0 << 16; c0y.u = a0 & 0xffff0000u;
                acc.x = fmaf(c0x.f, t0.x, acc.x); acc.y = fmaf(c0y.f, t0.y, acc.y);
            }
            *reinterpret_cast<float2*>(v + (size_t)i * DD + d0) = acc;
        }
    }
}

extern "C" void kernel_launch(void* const* d_in, const int* in_sizes, int n_in,
                              void* d_out, int out_size, void* d_ws, size_t ws_size,
                              hipStream_t stream)
{
    const float* x     = (const float*)d_in[0];
    const float* g     = (const float*)d_in[1];
    const int*   idx_i = (const int*)d_in[2];
    const int*   idx_j = (const int*)d_in[3];
    const float* u     = (const float*)d_in[5];
    const float* Wf    = (const float*)d_in[6];
    const float* bf    = (const float*)d_in[7];
    const float* Wg    = (const float*)d_in[8];
    const float* bg    = (const float*)d_in[9];
    const float* Wj    = (const float*)d_in[10];
    const float* bj    = (const float*)d_in[11];
    const float* Wi    = (const float*)d_in[12];
    const float* bi    = (const float*)d_in[13];
    const float* rw1   = (const float*)d_in[14];
    const float* rb1   = (const float*)d_in[15];
    const float* rw2   = (const float*)d_in[16];
    const float* rb2   = (const float*)d_in[17];

    const int N = in_sizes[0] / DD;   // 50000
    const int E = in_sizes[2];        // 640000
    float* out = (float*)d_out;

    // workspace layout
    float*          v     = (float*)d_ws;                           // [N,128] f32
    unsigned short* A     = (unsigned short*)(v + (size_t)N * DD);  // [N,128] bf16
    int*            cnt   = (int*)(A + (size_t)N * DD);
    int*            off   = cnt + N;
    int*            bsum  = off + N;                                // [64]
    int*            rank  = bsum + 64;                              // [E]
    int2*           spair = (int2*)(rank + E);                      // [E]
    unsigned short* Wb    = (unsigned short*)(spair + E);           // 9*16384 bf16
    unsigned short* gh    = Wb + 9 * 16384;                         // [E*20] fp16

    const size_t need_gh = (size_t)((char*)(gh + (size_t)E * 20) - (char*)d_ws);
    const bool gh_ok = ws_size >= need_gh;

    dim3 blk(256);
    const int tiles    = (N + 63) / 64;
    const int eblocks  = (E + 255) / 256;
    const int sblocks  = (N + 1023) / 1024;   // 49 for N=50000 (<=64 required)
    const int gchunks  = gh_ok ? (E * 20) / 8 : 0;
    const int gblocks  = gh_ok ? (gchunks + 255) / 256 : 0;

    // cnt must be zero before prep (hist folded in)
    hipMemsetAsync(cnt, 0, (size_t)N * sizeof(int), stream);

    prep_kernel<<<72 + gblocks + eblocks, blk, 0, stream>>>(
        Wj, Wi, rw1, rw2, Wf, Wb, g, gh, gchunks, gblocks, idx_i, cnt, rank, E);

    scan_reduce<<<sblocks, blk, 0, stream>>>(cnt, bsum, N);
    scan_apply<<<sblocks, blk, 0, stream>>>(cnt, bsum, off, N, sblocks);

    scatter_dual<<<eblocks + tiles, blk, 0, stream>>>(
        idx_i, idx_j, off, rank, spair, E, eblocks,
        x, Wb, bj, bi, A, v, N);

    if (gh_ok)
        agg_kernel<1><<<2048, blk, 0, stream>>>(off, cnt, spair, gh, g,
                                                Wg, bg, A, v, N);
    else
        agg_kernel<0><<<2048, blk, 0, stream>>>(off, cnt, spair, gh, g,
                                                Wg, bg, A, v, N);

    tail_kernel<<<tiles, blk, 0, stream>>>(v, x, Wb, rb1, rb2, bf, u, out, N);
}